// Round 1
// baseline (3951.431 us; speedup 1.0000x reference)
//
#include <hip/hip_runtime.h>
#include <math.h>

#define H 128
#define BN_EPS 1e-5f

// ---------------- Atom encoder: h[n][c] = sum_f table[x[n][f]+off[f]][c] ----
__global__ __launch_bounds__(256) void enc_kernel(const int* __restrict__ x,
    const float* __restrict__ table, float* __restrict__ h, int N)
{
    int idx = blockIdx.x * 256 + threadIdx.x;
    int node = idx >> 7;
    if (node >= N) return;
    int c = idx & 127;
    const int offs[9] = {0, 119, 123, 135, 147, 157, 163, 169, 171};
    const int* xr = x + node * 9;
    float s = 0.f;
#pragma unroll
    for (int f = 0; f < 9; ++f)
        s += table[(size_t)(xr[f] + offs[f]) * H + c];
    h[idx] = s;
}

// ---------------- degree (in-degree over col) --------------------------------
__global__ __launch_bounds__(256) void deg_kernel(const int* __restrict__ col,
                                                  float* __restrict__ deg, int E)
{
    int e = blockIdx.x * 256 + threadIdx.x;
    if (e < E) atomicAdd(&deg[col[e]], 1.0f);
}

__global__ __launch_bounds__(256) void dis_kernel(const float* __restrict__ deg,
                                                  float* __restrict__ dis, int N)
{
    int i = blockIdx.x * 256 + threadIdx.x;
    if (i < N) dis[i] = rsqrtf(deg[i] + 1.0f);  // +1 = self loop
}

// ---------------- GEMM: out[N][128] = h[N][128] @ W[128][128] ----------------
// 64-row tile, full 128 cols. W staged in LDS in two 64-k halves (32KB each).
// 256 threads: 8 row-groups x 32 col-groups; each thread 8 rows x 4 cols.
__global__ __launch_bounds__(256) void gemm_kernel(const float* __restrict__ h,
    const float* __restrict__ W, float* __restrict__ out, int N)
{
    __shared__ float hs[64 * 128];
    __shared__ float wsm[64 * 128];
    int tx = threadIdx.x;
    int rowBase = blockIdx.x * 64;

    const float4* h4 = (const float4*)h;
    float4* hs4 = (float4*)hs;
    for (int i = tx; i < 64 * 32; i += 256) {
        int r = i >> 5;
        int gr = rowBase + r;
        hs4[i] = (gr < N) ? h4[(size_t)gr * 32 + (i & 31)] : make_float4(0, 0, 0, 0);
    }

    int cg = tx & 31, rg = tx >> 5;
    int row0 = rg * 8;
    float acc[8][4];
#pragma unroll
    for (int i = 0; i < 8; ++i)
#pragma unroll
        for (int j = 0; j < 4; ++j) acc[i][j] = 0.f;

    const float4* W4 = (const float4*)W;
    float4* ws4 = (float4*)wsm;
    for (int phase = 0; phase < 2; ++phase) {
        __syncthreads();
        for (int i = tx; i < 64 * 32; i += 256)
            ws4[i] = W4[(size_t)(phase * 64 + (i >> 5)) * 32 + (i & 31)];
        __syncthreads();
#pragma unroll
        for (int k4 = 0; k4 < 16; ++k4) {
            float4 b0 = ws4[(k4 * 4 + 0) * 32 + cg];
            float4 b1 = ws4[(k4 * 4 + 1) * 32 + cg];
            float4 b2 = ws4[(k4 * 4 + 2) * 32 + cg];
            float4 b3 = ws4[(k4 * 4 + 3) * 32 + cg];
#pragma unroll
            for (int i = 0; i < 8; ++i) {
                float4 a = hs4[(row0 + i) * 32 + phase * 16 + k4];
                acc[i][0] += a.x * b0.x + a.y * b1.x + a.z * b2.x + a.w * b3.x;
                acc[i][1] += a.x * b0.y + a.y * b1.y + a.z * b2.y + a.w * b3.y;
                acc[i][2] += a.x * b0.z + a.y * b1.z + a.z * b2.z + a.w * b3.z;
                acc[i][3] += a.x * b0.w + a.y * b1.w + a.z * b2.w + a.w * b3.w;
            }
        }
    }

    float4* o4 = (float4*)out;
#pragma unroll
    for (int i = 0; i < 8; ++i) {
        int gr = rowBase + row0 + i;
        if (gr < N)
            o4[(size_t)gr * 32 + cg] = make_float4(acc[i][0], acc[i][1], acc[i][2], acc[i][3]);
    }
}

// ---------------- init agg: C = ht * dis^2 (self loop) + bias ----------------
__global__ __launch_bounds__(256) void init_agg_kernel(const float* __restrict__ B,
    const float* __restrict__ dis, const float* __restrict__ bias,
    float* __restrict__ C, int N)
{
    int i = blockIdx.x * 256 + threadIdx.x;
    int node = i >> 5;
    if (node >= N) return;
    int c4 = i & 31;
    float d = dis[node];
    float n2 = d * d;
    float4 v = ((const float4*)B)[i];
    float4 b = ((const float4*)bias)[c4];
    float4 o;
    o.x = v.x * n2 + b.x;
    o.y = v.y * n2 + b.y;
    o.z = v.z * n2 + b.z;
    o.w = v.w * n2 + b.w;
    ((float4*)C)[i] = o;
}

// ---------------- scatter: agg[col] += ht[row] * dis[row]*dis[col] -----------
// one wave (64 lanes) per edge; each lane handles 2 channels
__global__ __launch_bounds__(256) void scatter_kernel(const float* __restrict__ ht,
    const int* __restrict__ row, const int* __restrict__ col,
    const float* __restrict__ dis, float* __restrict__ agg, int E)
{
    int wave = blockIdx.x * 4 + (threadIdx.x >> 6);
    int lane = threadIdx.x & 63;
    if (wave >= E) return;
    int r = row[wave], c = col[wave];
    float nrm = dis[r] * dis[c];
    float2 v = ((const float2*)(ht + (size_t)r * H))[lane];
    float* dst = agg + (size_t)c * H + lane * 2;
    atomicAdd(dst, v.x * nrm);
    atomicAdd(dst + 1, v.y * nrm);
}

// ---------------- BN reduce: per-channel sum & sumsq -------------------------
__global__ __launch_bounds__(256) void bn_reduce_kernel(const float* __restrict__ C,
    float* __restrict__ stats, int N)
{
    __shared__ float ls[256];
    __shared__ float lq[256];
    int tx = threadIdx.x;
    int c = tx & 127, half = tx >> 7;
    int base = blockIdx.x * 256;
    float s = 0.f, q = 0.f;
    for (int r = half; r < 256; r += 2) {
        int gr = base + r;
        if (gr >= N) break;
        float v = C[(size_t)gr * H + c];
        s += v;
        q += v * v;
    }
    ls[tx] = s;
    lq[tx] = q;
    __syncthreads();
    if (half == 0) {
        atomicAdd(&stats[c], ls[tx] + ls[tx + 128]);
        atomicAdd(&stats[H + c], lq[tx] + lq[tx + 128]);
    }
}

// ---------------- BN finalize: scale/shift from stats ------------------------
__global__ void bn_finalize_kernel(float* __restrict__ stats,
    const float* __restrict__ gamma, const float* __restrict__ beta, float invN)
{
    int c = threadIdx.x;  // 128 threads
    float mean = stats[c] * invN;
    float var = stats[H + c] * invN - mean * mean;
    float inv = rsqrtf(var + BN_EPS);
    float sc = gamma[c] * inv;
    stats[2 * H + c] = sc;
    stats[3 * H + c] = beta[c] - mean * sc;
}

// ---------------- BN apply + relu + residual (in-place into A) ---------------
__global__ __launch_bounds__(256) void bn_apply_kernel(const float* __restrict__ C,
    const float* __restrict__ stats, float* __restrict__ A, int N, int relu)
{
    int i = blockIdx.x * 256 + threadIdx.x;
    int node = i >> 5;
    if (node >= N) return;
    int c4 = i & 31;
    float4 v = ((const float4*)C)[i];
    float4 sc = ((const float4*)(stats + 2 * H))[c4];
    float4 sh = ((const float4*)(stats + 3 * H))[c4];
    float4 r = ((const float4*)A)[i];
    float4 o;
    o.x = v.x * sc.x + sh.x;
    o.y = v.y * sc.y + sh.y;
    o.z = v.z * sc.z + sh.z;
    o.w = v.w * sc.w + sh.w;
    if (relu) {
        o.x = fmaxf(o.x, 0.f);
        o.y = fmaxf(o.y, 0.f);
        o.z = fmaxf(o.z, 0.f);
        o.w = fmaxf(o.w, 0.f);
    }
    o.x += r.x;
    o.y += r.y;
    o.z += r.z;
    o.w += r.w;
    ((float4*)A)[i] = o;
}

// ---------------- mean-pool scatter ------------------------------------------
__global__ __launch_bounds__(256) void pool_kernel(const float* __restrict__ A,
    const int* __restrict__ batch, float* __restrict__ pooled,
    float* __restrict__ counts, int N)
{
    int i = blockIdx.x * 256 + threadIdx.x;
    int node = i >> 5;
    if (node >= N) return;
    int c4 = i & 31;
    int g = batch[node];
    float4 v = ((const float4*)A)[i];
    float* dst = pooled + (size_t)g * H + c4 * 4;
    atomicAdd(dst + 0, v.x);
    atomicAdd(dst + 1, v.y);
    atomicAdd(dst + 2, v.z);
    atomicAdd(dst + 3, v.w);
    if (c4 == 0) atomicAdd(&counts[g], 1.0f);
}

// ---------------- final: sigmoid(mean . linW + b) ----------------------------
__global__ __launch_bounds__(256) void final_kernel(const float* __restrict__ pooled,
    const float* __restrict__ counts, const float* __restrict__ linW,
    const float* __restrict__ linb, float* __restrict__ out, int G)
{
    int g = blockIdx.x * 4 + (threadIdx.x >> 6);
    int lane = threadIdx.x & 63;
    if (g >= G) return;
    float2 p = ((const float2*)(pooled + (size_t)g * H))[lane];
    float2 w = ((const float2*)linW)[lane];
    float part = p.x * w.x + p.y * w.y;
#pragma unroll
    for (int off = 32; off > 0; off >>= 1)
        part += __shfl_down(part, off, 64);
    if (lane == 0) {
        float cnt = fmaxf(counts[g], 1.0f);
        float z = part / cnt + linb[0];
        out[g] = 1.0f / (1.0f + expf(-z));
    }
}

extern "C" void kernel_launch(void* const* d_in, const int* in_sizes, int n_in,
                              void* d_out, int out_size, void* d_ws, size_t ws_size,
                              hipStream_t stream)
{
    const int* x = (const int*)d_in[0];
    const int* ei = (const int*)d_in[1];
    const int* batch = (const int*)d_in[2];
    const float* table = (const float*)d_in[3];
    const float* convW = (const float*)d_in[4];
    const float* convB = (const float*)d_in[5];
    const float* gamma = (const float*)d_in[6];
    const float* beta = (const float*)d_in[7];
    const float* linW = (const float*)d_in[8];
    const float* linb = (const float*)d_in[9];
    float* out = (float*)d_out;

    int N = in_sizes[0] / 9;
    int E = in_sizes[1] / 2;
    int G = out_size;
    int L = in_sizes[4] / (H * H);
    const int* row = ei;
    const int* col = ei + E;

    float* ws = (float*)d_ws;
    float* deg = ws;                                 // N
    float* pooled = deg + N;                         // G*H
    float* counts = pooled + (size_t)G * H;          // G
    float* stats = counts + G;                       // L*4*H
    float* dis = stats + (size_t)L * 4 * H;          // N
    float* A = dis + N;                              // N*H  (h)
    float* B = A + (size_t)N * H;                    // N*H  (ht)
    float* C = B + (size_t)N * H;                    // N*H  (agg)

    size_t zero_bytes = (size_t)(N + (size_t)G * H + G + (size_t)L * 4 * H) * sizeof(float);
    hipMemsetAsync(d_ws, 0, zero_bytes, stream);

    enc_kernel<<<(N * 128 + 255) / 256, 256, 0, stream>>>(x, table, A, N);
    deg_kernel<<<(E + 255) / 256, 256, 0, stream>>>(col, deg, E);
    dis_kernel<<<(N + 255) / 256, 256, 0, stream>>>(deg, dis, N);

    for (int l = 0; l < L; ++l) {
        const float* Wl = convW + (size_t)l * H * H;
        float* st = stats + (size_t)l * 4 * H;
        gemm_kernel<<<(N + 63) / 64, 256, 0, stream>>>(A, Wl, B, N);
        init_agg_kernel<<<(N * 32 + 255) / 256, 256, 0, stream>>>(B, dis, convB + (size_t)l * H, C, N);
        scatter_kernel<<<(E + 3) / 4, 256, 0, stream>>>(B, row, col, dis, C, E);
        bn_reduce_kernel<<<(N + 255) / 256, 256, 0, stream>>>(C, st, N);
        bn_finalize_kernel<<<1, 128, 0, stream>>>(st, gamma + (size_t)l * H, beta + (size_t)l * H, 1.0f / (float)N);
        bn_apply_kernel<<<(N * 32 + 255) / 256, 256, 0, stream>>>(C, st, A, N, (l < L - 1) ? 1 : 0);
    }

    pool_kernel<<<(N * 32 + 255) / 256, 256, 0, stream>>>(A, batch, pooled, counts, N);
    final_kernel<<<(G + 3) / 4, 256, 0, stream>>>(pooled, counts, linW, linb, out, G);
}

// Round 2
// 1855.095 us; speedup vs baseline: 2.1300x; 2.1300x over previous
//
#include <hip/hip_runtime.h>
#include <math.h>

#define H 128
#define BN_EPS 1e-5f

// ---------------- Atom encoder: h[n][c] = sum_f table[x[n][f]+off[f]][c] ----
__global__ __launch_bounds__(256) void enc_kernel(const int* __restrict__ x,
    const float* __restrict__ table, float* __restrict__ h, int N)
{
    int idx = blockIdx.x * 256 + threadIdx.x;
    int node = idx >> 7;
    if (node >= N) return;
    int c = idx & 127;
    const int offs[9] = {0, 119, 123, 135, 147, 157, 163, 169, 171};
    const int* xr = x + node * 9;
    float s = 0.f;
#pragma unroll
    for (int f = 0; f < 9; ++f)
        s += table[(size_t)(xr[f] + offs[f]) * H + c];
    h[idx] = s;
}

// ---------------- degree (in-degree over col), int atomics -------------------
__global__ __launch_bounds__(256) void deg_kernel(const int* __restrict__ col,
                                                  int* __restrict__ deg, int E)
{
    int e = blockIdx.x * 256 + threadIdx.x;
    if (e < E) atomicAdd(&deg[col[e]], 1);
}

__global__ __launch_bounds__(256) void dis_kernel(const int* __restrict__ deg,
                                                  float* __restrict__ dis, int N)
{
    int i = blockIdx.x * 256 + threadIdx.x;
    if (i < N) dis[i] = rsqrtf((float)deg[i] + 1.0f);  // +1 = self loop
}

// ---------------- scan step 1: per-block sums of deg -------------------------
__global__ __launch_bounds__(256) void scan1_kernel(const int* __restrict__ deg,
    int* __restrict__ blockSums, int N)
{
    __shared__ int s[256];
    int t = threadIdx.x;
    int g = blockIdx.x * 256 + t;
    s[t] = (g < N) ? deg[g] : 0;
    __syncthreads();
#pragma unroll
    for (int off = 128; off > 0; off >>= 1) {
        if (t < off) s[t] += s[t + off];
        __syncthreads();
    }
    if (t == 0) blockSums[blockIdx.x] = s[0];
}

// ---------------- scan step 2: exclusive scan of block sums (<=512) ----------
__global__ __launch_bounds__(512) void scan2_kernel(int* __restrict__ blockSums, int NB)
{
    __shared__ int s[512];
    int t = threadIdx.x;
    int own = (t < NB) ? blockSums[t] : 0;
    s[t] = own;
    __syncthreads();
    for (int off = 1; off < 512; off <<= 1) {
        int v = (t >= off) ? s[t - off] : 0;
        __syncthreads();
        s[t] += v;
        __syncthreads();
    }
    if (t < NB) blockSums[t] = s[t] - own;  // exclusive
}

// ---------------- scan step 3: final row_ptr ---------------------------------
__global__ __launch_bounds__(256) void scan3_kernel(const int* __restrict__ deg,
    const int* __restrict__ blockOff, int* __restrict__ row_ptr, int N, int E)
{
    __shared__ int s[256];
    int t = threadIdx.x;
    int g = blockIdx.x * 256 + t;
    int own = (g < N) ? deg[g] : 0;
    s[t] = own;
    __syncthreads();
    for (int off = 1; off < 256; off <<= 1) {
        int v = (t >= off) ? s[t - off] : 0;
        __syncthreads();
        s[t] += v;
        __syncthreads();
    }
    if (g < N) row_ptr[g] = blockOff[blockIdx.x] + s[t] - own;
    if (g == N - 1) row_ptr[N] = E;
}

// ---------------- fill CSR: edge_data[pos] = {src, norm} ---------------------
__global__ __launch_bounds__(256) void fill_kernel(const int* __restrict__ row,
    const int* __restrict__ col, const int* __restrict__ row_ptr,
    int* __restrict__ cnt, const float* __restrict__ dis,
    float2* __restrict__ edge_data, int E)
{
    int e = blockIdx.x * 256 + threadIdx.x;
    if (e >= E) return;
    int r = row[e], c = col[e];
    int pos = row_ptr[c] + atomicAdd(&cnt[c], 1);
    edge_data[pos] = make_float2(__int_as_float(r), dis[r] * dis[c]);
}

// ---------------- GEMM: out[N][128] = h[N][128] @ W[128][128] ----------------
__global__ __launch_bounds__(256) void gemm_kernel(const float* __restrict__ h,
    const float* __restrict__ W, float* __restrict__ out, int N)
{
    __shared__ float hs[64 * 128];
    __shared__ float wsm[64 * 128];
    int tx = threadIdx.x;
    int rowBase = blockIdx.x * 64;

    const float4* h4 = (const float4*)h;
    float4* hs4 = (float4*)hs;
    for (int i = tx; i < 64 * 32; i += 256) {
        int r = i >> 5;
        int gr = rowBase + r;
        hs4[i] = (gr < N) ? h4[(size_t)gr * 32 + (i & 31)] : make_float4(0, 0, 0, 0);
    }

    int cg = tx & 31, rg = tx >> 5;
    int row0 = rg * 8;
    float acc[8][4];
#pragma unroll
    for (int i = 0; i < 8; ++i)
#pragma unroll
        for (int j = 0; j < 4; ++j) acc[i][j] = 0.f;

    const float4* W4 = (const float4*)W;
    float4* ws4 = (float4*)wsm;
    for (int phase = 0; phase < 2; ++phase) {
        __syncthreads();
        for (int i = tx; i < 64 * 32; i += 256)
            ws4[i] = W4[(size_t)(phase * 64 + (i >> 5)) * 32 + (i & 31)];
        __syncthreads();
#pragma unroll
        for (int k4 = 0; k4 < 16; ++k4) {
            float4 b0 = ws4[(k4 * 4 + 0) * 32 + cg];
            float4 b1 = ws4[(k4 * 4 + 1) * 32 + cg];
            float4 b2 = ws4[(k4 * 4 + 2) * 32 + cg];
            float4 b3 = ws4[(k4 * 4 + 3) * 32 + cg];
#pragma unroll
            for (int i = 0; i < 8; ++i) {
                float4 a = hs4[(row0 + i) * 32 + phase * 16 + k4];
                acc[i][0] += a.x * b0.x + a.y * b1.x + a.z * b2.x + a.w * b3.x;
                acc[i][1] += a.x * b0.y + a.y * b1.y + a.z * b2.y + a.w * b3.y;
                acc[i][2] += a.x * b0.z + a.y * b1.z + a.z * b2.z + a.w * b3.z;
                acc[i][3] += a.x * b0.w + a.y * b1.w + a.z * b2.w + a.w * b3.w;
            }
        }
    }

    float4* o4 = (float4*)out;
#pragma unroll
    for (int i = 0; i < 8; ++i) {
        int gr = rowBase + row0 + i;
        if (gr < N)
            o4[(size_t)gr * 32 + cg] = make_float4(acc[i][0], acc[i][1], acc[i][2], acc[i][3]);
    }
}

// ---------------- CSR aggregation, fused self-loop + bias --------------------
// one wave per node; each lane owns 2 channels (float2)
__global__ __launch_bounds__(256) void agg_kernel(const float* __restrict__ ht,
    const int* __restrict__ row_ptr, const float2* __restrict__ edge_data,
    const float* __restrict__ dis, const float* __restrict__ bias,
    float* __restrict__ C, int N)
{
    int wave = blockIdx.x * 4 + (threadIdx.x >> 6);
    int lane = threadIdx.x & 63;
    if (wave >= N) return;
    int start = row_ptr[wave], end = row_ptr[wave + 1];
    float d = dis[wave];
    float n2 = d * d;
    float2 v = ((const float2*)(ht + (size_t)wave * H))[lane];
    float2 b = ((const float2*)bias)[lane];
    float accx = v.x * n2 + b.x;
    float accy = v.y * n2 + b.y;
    for (int e = start; e < end; ++e) {
        float2 ed = edge_data[e];
        int s = __float_as_int(ed.x);
        float nrm = ed.y;
        float2 u = ((const float2*)(ht + (size_t)s * H))[lane];
        accx += u.x * nrm;
        accy += u.y * nrm;
    }
    ((float2*)(C + (size_t)wave * H))[lane] = make_float2(accx, accy);
}

// ---------------- BN reduce: per-channel sum & sumsq -------------------------
__global__ __launch_bounds__(256) void bn_reduce_kernel(const float* __restrict__ C,
    float* __restrict__ stats, int N)
{
    __shared__ float ls[256];
    __shared__ float lq[256];
    int tx = threadIdx.x;
    int c = tx & 127, half = tx >> 7;
    int base = blockIdx.x * 256;
    float s = 0.f, q = 0.f;
    for (int r = half; r < 256; r += 2) {
        int gr = base + r;
        if (gr >= N) break;
        float v = C[(size_t)gr * H + c];
        s += v;
        q += v * v;
    }
    ls[tx] = s;
    lq[tx] = q;
    __syncthreads();
    if (half == 0) {
        atomicAdd(&stats[c], ls[tx] + ls[tx + 128]);
        atomicAdd(&stats[H + c], lq[tx] + lq[tx + 128]);
    }
}

// ---------------- BN finalize: scale/shift from stats ------------------------
__global__ void bn_finalize_kernel(float* __restrict__ stats,
    const float* __restrict__ gamma, const float* __restrict__ beta, float invN)
{
    int c = threadIdx.x;  // 128 threads
    float mean = stats[c] * invN;
    float var = stats[H + c] * invN - mean * mean;
    float inv = rsqrtf(var + BN_EPS);
    float sc = gamma[c] * inv;
    stats[2 * H + c] = sc;
    stats[3 * H + c] = beta[c] - mean * sc;
}

// ---------------- BN apply + relu + residual (in-place into A) ---------------
__global__ __launch_bounds__(256) void bn_apply_kernel(const float* __restrict__ C,
    const float* __restrict__ stats, float* __restrict__ A, int N, int relu)
{
    int i = blockIdx.x * 256 + threadIdx.x;
    int node = i >> 5;
    if (node >= N) return;
    int c4 = i & 31;
    float4 v = ((const float4*)C)[i];
    float4 sc = ((const float4*)(stats + 2 * H))[c4];
    float4 sh = ((const float4*)(stats + 3 * H))[c4];
    float4 r = ((const float4*)A)[i];
    float4 o;
    o.x = v.x * sc.x + sh.x;
    o.y = v.y * sc.y + sh.y;
    o.z = v.z * sc.z + sh.z;
    o.w = v.w * sc.w + sh.w;
    if (relu) {
        o.x = fmaxf(o.x, 0.f);
        o.y = fmaxf(o.y, 0.f);
        o.z = fmaxf(o.z, 0.f);
        o.w = fmaxf(o.w, 0.f);
    }
    o.x += r.x;
    o.y += r.y;
    o.z += r.z;
    o.w += r.w;
    ((float4*)A)[i] = o;
}

// ---------------- mean-pool scatter ------------------------------------------
__global__ __launch_bounds__(256) void pool_kernel(const float* __restrict__ A,
    const int* __restrict__ batch, float* __restrict__ pooled,
    float* __restrict__ counts, int N)
{
    int i = blockIdx.x * 256 + threadIdx.x;
    int node = i >> 5;
    if (node >= N) return;
    int c4 = i & 31;
    int g = batch[node];
    float4 v = ((const float4*)A)[i];
    float* dst = pooled + (size_t)g * H + c4 * 4;
    atomicAdd(dst + 0, v.x);
    atomicAdd(dst + 1, v.y);
    atomicAdd(dst + 2, v.z);
    atomicAdd(dst + 3, v.w);
    if (c4 == 0) atomicAdd(&counts[g], 1.0f);
}

// ---------------- final: sigmoid(mean . linW + b) ----------------------------
__global__ __launch_bounds__(256) void final_kernel(const float* __restrict__ pooled,
    const float* __restrict__ counts, const float* __restrict__ linW,
    const float* __restrict__ linb, float* __restrict__ out, int G)
{
    int g = blockIdx.x * 4 + (threadIdx.x >> 6);
    int lane = threadIdx.x & 63;
    if (g >= G) return;
    float2 p = ((const float2*)(pooled + (size_t)g * H))[lane];
    float2 w = ((const float2*)linW)[lane];
    float part = p.x * w.x + p.y * w.y;
#pragma unroll
    for (int off = 32; off > 0; off >>= 1)
        part += __shfl_down(part, off, 64);
    if (lane == 0) {
        float cnt = fmaxf(counts[g], 1.0f);
        float z = part / cnt + linb[0];
        out[g] = 1.0f / (1.0f + expf(-z));
    }
}

static inline size_t align4(size_t x) { return (x + 3) & ~(size_t)3; }  // 16B align (in floats)

extern "C" void kernel_launch(void* const* d_in, const int* in_sizes, int n_in,
                              void* d_out, int out_size, void* d_ws, size_t ws_size,
                              hipStream_t stream)
{
    const int* x = (const int*)d_in[0];
    const int* ei = (const int*)d_in[1];
    const int* batch = (const int*)d_in[2];
    const float* table = (const float*)d_in[3];
    const float* convW = (const float*)d_in[4];
    const float* convB = (const float*)d_in[5];
    const float* gamma = (const float*)d_in[6];
    const float* beta = (const float*)d_in[7];
    const float* linW = (const float*)d_in[8];
    const float* linb = (const float*)d_in[9];
    float* out = (float*)d_out;

    int N = in_sizes[0] / 9;
    int E = in_sizes[1] / 2;
    int G = out_size;
    int L = in_sizes[4] / (H * H);
    const int* row = ei;
    const int* col = ei + E;
    int NB = (N + 255) / 256;  // blocks for scan (must be <= 512)

    float* ws = (float*)d_ws;
    size_t off = 0;
    // ---- zeroed region ----
    int* deg = (int*)(ws + off);        off = align4(off + N);
    int* cnt = (int*)(ws + off);        off = align4(off + N);
    float* pooled = ws + off;           off = align4(off + (size_t)G * H);
    float* counts = ws + off;           off = align4(off + G);
    float* stats = ws + off;            off = align4(off + (size_t)L * 4 * H);
    size_t zero_bytes = off * sizeof(float);
    // ---- non-zeroed ----
    float* dis = ws + off;              off = align4(off + N);
    int* row_ptr = (int*)(ws + off);    off = align4(off + N + 1);
    int* blockSums = (int*)(ws + off);  off = align4(off + 512);
    float2* edge_data = (float2*)(ws + off); off = align4(off + (size_t)2 * E);
    float* A = ws + off;                off += (size_t)N * H;
    float* B = ws + off;                off += (size_t)N * H;
    float* C = ws + off;                off += (size_t)N * H;

    hipMemsetAsync(d_ws, 0, zero_bytes, stream);

    enc_kernel<<<(N * 128 + 255) / 256, 256, 0, stream>>>(x, table, A, N);
    deg_kernel<<<(E + 255) / 256, 256, 0, stream>>>(col, deg, E);
    dis_kernel<<<(N + 255) / 256, 256, 0, stream>>>(deg, dis, N);
    scan1_kernel<<<NB, 256, 0, stream>>>(deg, blockSums, N);
    scan2_kernel<<<1, 512, 0, stream>>>(blockSums, NB);
    scan3_kernel<<<NB, 256, 0, stream>>>(deg, blockSums, row_ptr, N, E);
    fill_kernel<<<(E + 255) / 256, 256, 0, stream>>>(row, col, row_ptr, cnt, dis, edge_data, E);

    for (int l = 0; l < L; ++l) {
        const float* Wl = convW + (size_t)l * H * H;
        float* st = stats + (size_t)l * 4 * H;
        gemm_kernel<<<(N + 63) / 64, 256, 0, stream>>>(A, Wl, B, N);
        agg_kernel<<<(N + 3) / 4, 256, 0, stream>>>(B, row_ptr, edge_data, dis,
                                                    convB + (size_t)l * H, C, N);
        bn_reduce_kernel<<<NB, 256, 0, stream>>>(C, st, N);
        bn_finalize_kernel<<<1, 128, 0, stream>>>(st, gamma + (size_t)l * H, beta + (size_t)l * H, 1.0f / (float)N);
        bn_apply_kernel<<<(N * 32 + 255) / 256, 256, 0, stream>>>(C, st, A, N, (l < L - 1) ? 1 : 0);
    }

    pool_kernel<<<(N * 32 + 255) / 256, 256, 0, stream>>>(A, batch, pooled, counts, N);
    final_kernel<<<(G + 3) / 4, 256, 0, stream>>>(pooled, counts, linW, linb, out, G);
}

// Round 3
// 1538.719 us; speedup vs baseline: 2.5680x; 1.2056x over previous
//
#include <hip/hip_runtime.h>
#include <math.h>

#define H 128
#define BN_EPS 1e-5f

// ---------------- Atom encoder: h[n][c] = sum_f table[x[n][f]+off[f]][c] ----
__global__ __launch_bounds__(256) void enc_kernel(const int* __restrict__ x,
    const float* __restrict__ table, float* __restrict__ h, int N)
{
    int idx = blockIdx.x * 256 + threadIdx.x;
    int node = idx >> 7;
    if (node >= N) return;
    int c = idx & 127;
    const int offs[9] = {0, 119, 123, 135, 147, 157, 163, 169, 171};
    const int* xr = x + node * 9;
    float s = 0.f;
#pragma unroll
    for (int f = 0; f < 9; ++f)
        s += table[(size_t)(xr[f] + offs[f]) * H + c];
    h[idx] = s;
}

// ---------------- degree (in-degree over col), int atomics -------------------
__global__ __launch_bounds__(256) void deg_kernel(const int* __restrict__ col,
                                                  int* __restrict__ deg, int E)
{
    int e = blockIdx.x * 256 + threadIdx.x;
    if (e < E) atomicAdd(&deg[col[e]], 1);
}

__global__ __launch_bounds__(256) void dis_kernel(const int* __restrict__ deg,
                                                  float* __restrict__ dis, int N)
{
    int i = blockIdx.x * 256 + threadIdx.x;
    if (i < N) dis[i] = rsqrtf((float)deg[i] + 1.0f);  // +1 = self loop
}

// ---------------- scan step 1: per-block sums of deg -------------------------
__global__ __launch_bounds__(256) void scan1_kernel(const int* __restrict__ deg,
    int* __restrict__ blockSums, int N)
{
    __shared__ int s[256];
    int t = threadIdx.x;
    int g = blockIdx.x * 256 + t;
    s[t] = (g < N) ? deg[g] : 0;
    __syncthreads();
#pragma unroll
    for (int off = 128; off > 0; off >>= 1) {
        if (t < off) s[t] += s[t + off];
        __syncthreads();
    }
    if (t == 0) blockSums[blockIdx.x] = s[0];
}

// ---------------- scan step 2: exclusive scan of block sums (<=512) ----------
__global__ __launch_bounds__(512) void scan2_kernel(int* __restrict__ blockSums, int NB)
{
    __shared__ int s[512];
    int t = threadIdx.x;
    int own = (t < NB) ? blockSums[t] : 0;
    s[t] = own;
    __syncthreads();
    for (int off = 1; off < 512; off <<= 1) {
        int v = (t >= off) ? s[t - off] : 0;
        __syncthreads();
        s[t] += v;
        __syncthreads();
    }
    if (t < NB) blockSums[t] = s[t] - own;  // exclusive
}

// ---------------- scan step 3: final row_ptr ---------------------------------
__global__ __launch_bounds__(256) void scan3_kernel(const int* __restrict__ deg,
    const int* __restrict__ blockOff, int* __restrict__ row_ptr, int N, int E)
{
    __shared__ int s[256];
    int t = threadIdx.x;
    int g = blockIdx.x * 256 + t;
    int own = (g < N) ? deg[g] : 0;
    s[t] = own;
    __syncthreads();
    for (int off = 1; off < 256; off <<= 1) {
        int v = (t >= off) ? s[t - off] : 0;
        __syncthreads();
        s[t] += v;
        __syncthreads();
    }
    if (g < N) row_ptr[g] = blockOff[blockIdx.x] + s[t] - own;
    if (g == N - 1) row_ptr[N] = E;
}

// ---------------- fill CSR: edge_data[pos] = {src, norm} ---------------------
__global__ __launch_bounds__(256) void fill_kernel(const int* __restrict__ row,
    const int* __restrict__ col, const int* __restrict__ row_ptr,
    int* __restrict__ cnt, const float* __restrict__ dis,
    float2* __restrict__ edge_data, int E)
{
    int e = blockIdx.x * 256 + threadIdx.x;
    if (e >= E) return;
    int r = row[e], c = col[e];
    int pos = row_ptr[c] + atomicAdd(&cnt[c], 1);
    edge_data[pos] = make_float2(__int_as_float(r), dis[r] * dis[c]);
}

// ---------------- GEMM: out[N][128] = h[N][128] @ W[128][128] ----------------
__global__ __launch_bounds__(256) void gemm_kernel(const float* __restrict__ h,
    const float* __restrict__ W, float* __restrict__ out, int N)
{
    __shared__ float hs[64 * 128];
    __shared__ float wsm[64 * 128];
    int tx = threadIdx.x;
    int rowBase = blockIdx.x * 64;

    const float4* h4 = (const float4*)h;
    float4* hs4 = (float4*)hs;
    for (int i = tx; i < 64 * 32; i += 256) {
        int r = i >> 5;
        int gr = rowBase + r;
        hs4[i] = (gr < N) ? h4[(size_t)gr * 32 + (i & 31)] : make_float4(0, 0, 0, 0);
    }

    int cg = tx & 31, rg = tx >> 5;
    int row0 = rg * 8;
    float acc[8][4];
#pragma unroll
    for (int i = 0; i < 8; ++i)
#pragma unroll
        for (int j = 0; j < 4; ++j) acc[i][j] = 0.f;

    const float4* W4 = (const float4*)W;
    float4* ws4 = (float4*)wsm;
    for (int phase = 0; phase < 2; ++phase) {
        __syncthreads();
        for (int i = tx; i < 64 * 32; i += 256)
            ws4[i] = W4[(size_t)(phase * 64 + (i >> 5)) * 32 + (i & 31)];
        __syncthreads();
#pragma unroll
        for (int k4 = 0; k4 < 16; ++k4) {
            float4 b0 = ws4[(k4 * 4 + 0) * 32 + cg];
            float4 b1 = ws4[(k4 * 4 + 1) * 32 + cg];
            float4 b2 = ws4[(k4 * 4 + 2) * 32 + cg];
            float4 b3 = ws4[(k4 * 4 + 3) * 32 + cg];
#pragma unroll
            for (int i = 0; i < 8; ++i) {
                float4 a = hs4[(row0 + i) * 32 + phase * 16 + k4];
                acc[i][0] += a.x * b0.x + a.y * b1.x + a.z * b2.x + a.w * b3.x;
                acc[i][1] += a.x * b0.y + a.y * b1.y + a.z * b2.y + a.w * b3.y;
                acc[i][2] += a.x * b0.z + a.y * b1.z + a.z * b2.z + a.w * b3.z;
                acc[i][3] += a.x * b0.w + a.y * b1.w + a.z * b2.w + a.w * b3.w;
            }
        }
    }

    float4* o4 = (float4*)out;
#pragma unroll
    for (int i = 0; i < 8; ++i) {
        int gr = rowBase + row0 + i;
        if (gr < N)
            o4[(size_t)gr * 32 + cg] = make_float4(acc[i][0], acc[i][1], acc[i][2], acc[i][3]);
    }
}

// ---------------- CSR aggregation, fused self-loop + bias --------------------
// one wave per node; each lane owns 2 channels (float2)
__global__ __launch_bounds__(256) void agg_kernel(const float* __restrict__ ht,
    const int* __restrict__ row_ptr, const float2* __restrict__ edge_data,
    const float* __restrict__ dis, const float* __restrict__ bias,
    float* __restrict__ C, int N)
{
    int wave = blockIdx.x * 4 + (threadIdx.x >> 6);
    int lane = threadIdx.x & 63;
    if (wave >= N) return;
    int start = row_ptr[wave], end = row_ptr[wave + 1];
    float d = dis[wave];
    float n2 = d * d;
    float2 v = ((const float2*)(ht + (size_t)wave * H))[lane];
    float2 b = ((const float2*)bias)[lane];
    float accx = v.x * n2 + b.x;
    float accy = v.y * n2 + b.y;
    for (int e = start; e < end; ++e) {
        float2 ed = edge_data[e];
        int s = __float_as_int(ed.x);
        float nrm = ed.y;
        float2 u = ((const float2*)(ht + (size_t)s * H))[lane];
        accx += u.x * nrm;
        accy += u.y * nrm;
    }
    ((float2*)(C + (size_t)wave * H))[lane] = make_float2(accx, accy);
}

// ---------------- BN reduce: per-channel sum & sumsq -------------------------
__global__ __launch_bounds__(256) void bn_reduce_kernel(const float* __restrict__ C,
    float* __restrict__ stats, int N)
{
    __shared__ float ls[256];
    __shared__ float lq[256];
    int tx = threadIdx.x;
    int c = tx & 127, half = tx >> 7;
    int base = blockIdx.x * 256;
    float s = 0.f, q = 0.f;
    for (int r = half; r < 256; r += 2) {
        int gr = base + r;
        if (gr >= N) break;
        float v = C[(size_t)gr * H + c];
        s += v;
        q += v * v;
    }
    ls[tx] = s;
    lq[tx] = q;
    __syncthreads();
    if (half == 0) {
        atomicAdd(&stats[c], ls[tx] + ls[tx + 128]);
        atomicAdd(&stats[H + c], lq[tx] + lq[tx + 128]);
    }
}

// ---------------- BN finalize: scale/shift from stats ------------------------
__global__ void bn_finalize_kernel(float* __restrict__ stats,
    const float* __restrict__ gamma, const float* __restrict__ beta, float invN)
{
    int c = threadIdx.x;  // 128 threads
    float mean = stats[c] * invN;
    float var = stats[H + c] * invN - mean * mean;
    float inv = rsqrtf(var + BN_EPS);
    float sc = gamma[c] * inv;
    stats[2 * H + c] = sc;
    stats[3 * H + c] = beta[c] - mean * sc;
}

// ---------------- BN apply + relu + residual (in-place into A) ---------------
__global__ __launch_bounds__(256) void bn_apply_kernel(const float* __restrict__ C,
    const float* __restrict__ stats, float* __restrict__ A, int N, int relu)
{
    int i = blockIdx.x * 256 + threadIdx.x;
    int node = i >> 5;
    if (node >= N) return;
    int c4 = i & 31;
    float4 v = ((const float4*)C)[i];
    float4 sc = ((const float4*)(stats + 2 * H))[c4];
    float4 sh = ((const float4*)(stats + 3 * H))[c4];
    float4 r = ((const float4*)A)[i];
    float4 o;
    o.x = v.x * sc.x + sh.x;
    o.y = v.y * sc.y + sh.y;
    o.z = v.z * sc.z + sh.z;
    o.w = v.w * sc.w + sh.w;
    if (relu) {
        o.x = fmaxf(o.x, 0.f);
        o.y = fmaxf(o.y, 0.f);
        o.z = fmaxf(o.z, 0.f);
        o.w = fmaxf(o.w, 0.f);
    }
    o.x += r.x;
    o.y += r.y;
    o.z += r.z;
    o.w += r.w;
    ((float4*)A)[i] = o;
}

// ---------------- mean-pool: segmented reduction over sorted batch_idx -------
// 128 threads/block = one thread per channel; each block owns ROWS consecutive
// rows; register-accumulate runs of equal graph id, flush once per run.
#define POOL_ROWS 64
__global__ __launch_bounds__(128) void pool_kernel(const float* __restrict__ A,
    const int* __restrict__ batch, float* __restrict__ pooled,
    float* __restrict__ counts, int N)
{
    int c = threadIdx.x;
    int base = blockIdx.x * POOL_ROWS;
    int end = base + POOL_ROWS;
    if (end > N) end = N;
    if (base >= N) return;
    int curg = batch[base];
    int runStart = base;
    float acc = 0.f;
    for (int r = base; r < end; ++r) {
        int g = batch[r];
        if (g != curg) {
            atomicAdd(&pooled[(size_t)curg * H + c], acc);
            if (c == 0) atomicAdd(&counts[curg], (float)(r - runStart));
            curg = g;
            acc = 0.f;
            runStart = r;
        }
        acc += A[(size_t)r * H + c];
    }
    atomicAdd(&pooled[(size_t)curg * H + c], acc);
    if (c == 0) atomicAdd(&counts[curg], (float)(end - runStart));
}

// ---------------- final: sigmoid(mean . linW + b) ----------------------------
__global__ __launch_bounds__(256) void final_kernel(const float* __restrict__ pooled,
    const float* __restrict__ counts, const float* __restrict__ linW,
    const float* __restrict__ linb, float* __restrict__ out, int G)
{
    int g = blockIdx.x * 4 + (threadIdx.x >> 6);
    int lane = threadIdx.x & 63;
    if (g >= G) return;
    float2 p = ((const float2*)(pooled + (size_t)g * H))[lane];
    float2 w = ((const float2*)linW)[lane];
    float part = p.x * w.x + p.y * w.y;
#pragma unroll
    for (int off = 32; off > 0; off >>= 1)
        part += __shfl_down(part, off, 64);
    if (lane == 0) {
        float cnt = fmaxf(counts[g], 1.0f);
        float z = part / cnt + linb[0];
        out[g] = 1.0f / (1.0f + expf(-z));
    }
}

static inline size_t align4(size_t x) { return (x + 3) & ~(size_t)3; }  // 16B align (in floats)

extern "C" void kernel_launch(void* const* d_in, const int* in_sizes, int n_in,
                              void* d_out, int out_size, void* d_ws, size_t ws_size,
                              hipStream_t stream)
{
    const int* x = (const int*)d_in[0];
    const int* ei = (const int*)d_in[1];
    const int* batch = (const int*)d_in[2];
    const float* table = (const float*)d_in[3];
    const float* convW = (const float*)d_in[4];
    const float* convB = (const float*)d_in[5];
    const float* gamma = (const float*)d_in[6];
    const float* beta = (const float*)d_in[7];
    const float* linW = (const float*)d_in[8];
    const float* linb = (const float*)d_in[9];
    float* out = (float*)d_out;

    int N = in_sizes[0] / 9;
    int E = in_sizes[1] / 2;
    int G = out_size;
    int L = in_sizes[4] / (H * H);
    const int* row = ei;
    const int* col = ei + E;
    int NB = (N + 255) / 256;  // blocks for scan (must be <= 512)

    float* ws = (float*)d_ws;
    size_t off = 0;
    // ---- zeroed region ----
    int* deg = (int*)(ws + off);        off = align4(off + N);
    int* cnt = (int*)(ws + off);        off = align4(off + N);
    float* pooled = ws + off;           off = align4(off + (size_t)G * H);
    float* counts = ws + off;           off = align4(off + G);
    float* stats = ws + off;            off = align4(off + (size_t)L * 4 * H);
    size_t zero_bytes = off * sizeof(float);
    // ---- non-zeroed ----
    float* dis = ws + off;              off = align4(off + N);
    int* row_ptr = (int*)(ws + off);    off = align4(off + N + 1);
    int* blockSums = (int*)(ws + off);  off = align4(off + 512);
    float2* edge_data = (float2*)(ws + off); off = align4(off + (size_t)2 * E);
    float* A = ws + off;                off += (size_t)N * H;
    float* B = ws + off;                off += (size_t)N * H;
    float* C = ws + off;                off += (size_t)N * H;

    hipMemsetAsync(d_ws, 0, zero_bytes, stream);

    enc_kernel<<<(N * 128 + 255) / 256, 256, 0, stream>>>(x, table, A, N);
    deg_kernel<<<(E + 255) / 256, 256, 0, stream>>>(col, deg, E);
    dis_kernel<<<(N + 255) / 256, 256, 0, stream>>>(deg, dis, N);
    scan1_kernel<<<NB, 256, 0, stream>>>(deg, blockSums, N);
    scan2_kernel<<<1, 512, 0, stream>>>(blockSums, NB);
    scan3_kernel<<<NB, 256, 0, stream>>>(deg, blockSums, row_ptr, N, E);
    fill_kernel<<<(E + 255) / 256, 256, 0, stream>>>(row, col, row_ptr, cnt, dis, edge_data, E);

    for (int l = 0; l < L; ++l) {
        const float* Wl = convW + (size_t)l * H * H;
        float* st = stats + (size_t)l * 4 * H;
        gemm_kernel<<<(N + 63) / 64, 256, 0, stream>>>(A, Wl, B, N);
        agg_kernel<<<(N + 3) / 4, 256, 0, stream>>>(B, row_ptr, edge_data, dis,
                                                    convB + (size_t)l * H, C, N);
        bn_reduce_kernel<<<NB, 256, 0, stream>>>(C, st, N);
        bn_finalize_kernel<<<1, 128, 0, stream>>>(st, gamma + (size_t)l * H, beta + (size_t)l * H, 1.0f / (float)N);
        bn_apply_kernel<<<(N * 32 + 255) / 256, 256, 0, stream>>>(C, st, A, N, (l < L - 1) ? 1 : 0);
    }

    pool_kernel<<<(N + POOL_ROWS - 1) / POOL_ROWS, 128, 0, stream>>>(A, batch, pooled, counts, N);
    final_kernel<<<(G + 3) / 4, 256, 0, stream>>>(pooled, counts, linW, linb, out, G);
}

// Round 4
// 1114.729 us; speedup vs baseline: 3.5447x; 1.3804x over previous
//
#include <hip/hip_runtime.h>
#include <math.h>

#define H 128
#define BN_EPS 1e-5f

typedef float float4v __attribute__((ext_vector_type(4)));
typedef short short8v __attribute__((ext_vector_type(8)));
typedef unsigned short ushort4v __attribute__((ext_vector_type(4)));
typedef unsigned short ushort8v __attribute__((ext_vector_type(8)));

__device__ inline unsigned short bf16h(float x) {
    unsigned int u = __float_as_uint(x);
    return (unsigned short)((u + 0x7fffu + ((u >> 16) & 1u)) >> 16);
}
__device__ inline float bf16f(unsigned short h) {
    return __uint_as_float(((unsigned int)h) << 16);
}

// ---------------- Atom encoder: h[n][c] = sum_f table[x[n][f]+off[f]][c] ----
__global__ __launch_bounds__(256) void enc_kernel(const int* __restrict__ x,
    const float* __restrict__ table, float* __restrict__ h, int N)
{
    int idx = blockIdx.x * 256 + threadIdx.x;
    int node = idx >> 7;
    if (node >= N) return;
    int c = idx & 127;
    const int offs[9] = {0, 119, 123, 135, 147, 157, 163, 169, 171};
    const int* xr = x + node * 9;
    float s = 0.f;
#pragma unroll
    for (int f = 0; f < 9; ++f)
        s += table[(size_t)(xr[f] + offs[f]) * H + c];
    h[idx] = s;
}

// ---------------- degree (in-degree over col), int atomics -------------------
__global__ __launch_bounds__(256) void deg_kernel(const int* __restrict__ col,
                                                  int* __restrict__ deg, int E)
{
    int e = blockIdx.x * 256 + threadIdx.x;
    if (e < E) atomicAdd(&deg[col[e]], 1);
}

__global__ __launch_bounds__(256) void dis_kernel(const int* __restrict__ deg,
                                                  float* __restrict__ dis, int N)
{
    int i = blockIdx.x * 256 + threadIdx.x;
    if (i < N) dis[i] = rsqrtf((float)deg[i] + 1.0f);  // +1 = self loop
}

// ---------------- scan step 1: per-block sums of deg -------------------------
__global__ __launch_bounds__(256) void scan1_kernel(const int* __restrict__ deg,
    int* __restrict__ blockSums, int N)
{
    __shared__ int s[256];
    int t = threadIdx.x;
    int g = blockIdx.x * 256 + t;
    s[t] = (g < N) ? deg[g] : 0;
    __syncthreads();
#pragma unroll
    for (int off = 128; off > 0; off >>= 1) {
        if (t < off) s[t] += s[t + off];
        __syncthreads();
    }
    if (t == 0) blockSums[blockIdx.x] = s[0];
}

// ---------------- scan step 2: exclusive scan of block sums (<=512) ----------
__global__ __launch_bounds__(512) void scan2_kernel(int* __restrict__ blockSums, int NB)
{
    __shared__ int s[512];
    int t = threadIdx.x;
    int own = (t < NB) ? blockSums[t] : 0;
    s[t] = own;
    __syncthreads();
    for (int off = 1; off < 512; off <<= 1) {
        int v = (t >= off) ? s[t - off] : 0;
        __syncthreads();
        s[t] += v;
        __syncthreads();
    }
    if (t < NB) blockSums[t] = s[t] - own;  // exclusive
}

// ---------------- scan step 3: final row_ptr ---------------------------------
__global__ __launch_bounds__(256) void scan3_kernel(const int* __restrict__ deg,
    const int* __restrict__ blockOff, int* __restrict__ row_ptr, int N, int E)
{
    __shared__ int s[256];
    int t = threadIdx.x;
    int g = blockIdx.x * 256 + t;
    int own = (g < N) ? deg[g] : 0;
    s[t] = own;
    __syncthreads();
    for (int off = 1; off < 256; off <<= 1) {
        int v = (t >= off) ? s[t - off] : 0;
        __syncthreads();
        s[t] += v;
        __syncthreads();
    }
    if (g < N) row_ptr[g] = blockOff[blockIdx.x] + s[t] - own;
    if (g == N - 1) row_ptr[N] = E;
}

// ---------------- fill CSR: edge_data[pos] = {src, norm} ---------------------
__global__ __launch_bounds__(256) void fill_kernel(const int* __restrict__ row,
    const int* __restrict__ col, const int* __restrict__ row_ptr,
    int* __restrict__ cnt, const float* __restrict__ dis,
    float2* __restrict__ edge_data, int E)
{
    int e = blockIdx.x * 256 + threadIdx.x;
    if (e >= E) return;
    int r = row[e], c = col[e];
    int pos = row_ptr[c] + atomicAdd(&cnt[c], 1);
    edge_data[pos] = make_float2(__int_as_float(r), dis[r] * dis[c]);
}

// ---------------- W prep: Wt_hi/lo[l][n][k] = bf16split(W[l][k][n]) ----------
// grid = L*128 blocks (one per (l,k)), 128 threads (n)
__global__ __launch_bounds__(128) void wprep_kernel(const float* __restrict__ W,
    unsigned short* __restrict__ wt, int L)
{
    int b = blockIdx.x;
    int l = b >> 7, k = b & 127;
    int n = threadIdx.x;
    float x = W[(size_t)l * H * H + (size_t)k * H + n];
    unsigned short hi = bf16h(x);
    unsigned short lo = bf16h(x - bf16f(hi));
    unsigned short* base = wt + (size_t)l * 2 * H * H;
    base[(size_t)n * H + k] = hi;                       // hi block [n][k]
    base[(size_t)H * H + (size_t)n * H + k] = lo;       // lo block [n][k]
}

// ---------------- MFMA GEMM: out[N][128] = A[N][128] @ W[128][128] -----------
// split-bf16: A = Ah+Al, W = Wh+Wl; acc += AhWh + AhWl + AlWh  (AlWl ~2^-18)
// 128x128 tile, 4 waves (2x2 of 64x64), BK=32, 4 k-chunks.
#define LSTR 40  // LDS row stride in shorts (padded from 32)
__global__ __launch_bounds__(256) void gemm_mfma_kernel(const float* __restrict__ A,
    const unsigned short* __restrict__ wthi, float* __restrict__ out, int N)
{
    __shared__ unsigned short Ah[128 * LSTR];
    __shared__ unsigned short Al[128 * LSTR];
    __shared__ unsigned short Bh[128 * LSTR];
    __shared__ unsigned short Bl[128 * LSTR];

    const unsigned short* wtlo = wthi + H * H;
    const int tx = threadIdx.x;
    const int rowBase = blockIdx.x * 128;
    const int lane = tx & 63;
    const int w = tx >> 6;
    const int rw = (w & 1) * 64;
    const int cw = (w >> 1) * 64;
    const int mrow = lane & 15;
    const int quad = lane >> 4;

    float4v acc[4][4];
#pragma unroll
    for (int i = 0; i < 4; ++i)
#pragma unroll
        for (int j = 0; j < 4; ++j)
            acc[i][j] = (float4v)(0.f);

    const float4* A4 = (const float4*)A;

    for (int kk = 0; kk < 128; kk += 32) {
        __syncthreads();
        // ---- stage A chunk: rows rowBase..+127, cols kk..kk+31, fp32->bf16 hi/lo
#pragma unroll
        for (int i = 0; i < 4; ++i) {
            int idx = i * 256 + tx;          // 0..1023
            int r = idx >> 3;                // 0..127
            int f4 = idx & 7;                // float4 within 32-col chunk
            int gr = rowBase + r;
            float4 v = (gr < N) ? A4[(size_t)gr * 32 + (kk >> 2) + f4]
                                : make_float4(0.f, 0.f, 0.f, 0.f);
            unsigned short h0 = bf16h(v.x), h1 = bf16h(v.y), h2 = bf16h(v.z), h3 = bf16h(v.w);
            ushort4v hv = {h0, h1, h2, h3};
            ushort4v lv = {bf16h(v.x - bf16f(h0)), bf16h(v.y - bf16f(h1)),
                           bf16h(v.z - bf16f(h2)), bf16h(v.w - bf16f(h3))};
            *(ushort4v*)&Ah[r * LSTR + f4 * 4] = hv;
            *(ushort4v*)&Al[r * LSTR + f4 * 4] = lv;
        }
        // ---- stage Wt chunk: Wt[n][kk..kk+31] (already bf16, [n][k] layout)
#pragma unroll
        for (int i = 0; i < 2; ++i) {
            int idx = i * 256 + tx;          // 0..511
            int n = idx >> 2;                // 0..127
            int q = idx & 3;                 // 8-short segment
            *(ushort8v*)&Bh[n * LSTR + q * 8] = *(const ushort8v*)&wthi[(size_t)n * H + kk + q * 8];
            *(ushort8v*)&Bl[n * LSTR + q * 8] = *(const ushort8v*)&wtlo[(size_t)n * H + kk + q * 8];
        }
        __syncthreads();

        // ---- fragments
        short8v ah[4], al[4], bh[4], bl[4];
#pragma unroll
        for (int t = 0; t < 4; ++t) {
            ah[t] = *(const short8v*)&Ah[(rw + t * 16 + mrow) * LSTR + quad * 8];
            al[t] = *(const short8v*)&Al[(rw + t * 16 + mrow) * LSTR + quad * 8];
            bh[t] = *(const short8v*)&Bh[(cw + t * 16 + mrow) * LSTR + quad * 8];
            bl[t] = *(const short8v*)&Bl[(cw + t * 16 + mrow) * LSTR + quad * 8];
        }
#pragma unroll
        for (int ti = 0; ti < 4; ++ti)
#pragma unroll
            for (int tj = 0; tj < 4; ++tj) {
                acc[ti][tj] = __builtin_amdgcn_mfma_f32_16x16x32_bf16(ah[ti], bh[tj], acc[ti][tj], 0, 0, 0);
                acc[ti][tj] = __builtin_amdgcn_mfma_f32_16x16x32_bf16(ah[ti], bl[tj], acc[ti][tj], 0, 0, 0);
                acc[ti][tj] = __builtin_amdgcn_mfma_f32_16x16x32_bf16(al[ti], bh[tj], acc[ti][tj], 0, 0, 0);
            }
    }

    // ---- epilogue: D row = quad*4+i, col = mrow (within 16x16 tile)
#pragma unroll
    for (int ti = 0; ti < 4; ++ti) {
#pragma unroll
        for (int i = 0; i < 4; ++i) {
            int gr = rowBase + rw + ti * 16 + quad * 4 + i;
            if (gr < N) {
#pragma unroll
                for (int tj = 0; tj < 4; ++tj)
                    out[(size_t)gr * H + cw + tj * 16 + mrow] = acc[ti][tj][i];
            }
        }
    }
}

// ---------------- CSR aggregation, fused self-loop + bias --------------------
// one wave per node; each lane owns 2 channels (float2)
__global__ __launch_bounds__(256) void agg_kernel(const float* __restrict__ ht,
    const int* __restrict__ row_ptr, const float2* __restrict__ edge_data,
    const float* __restrict__ dis, const float* __restrict__ bias,
    float* __restrict__ C, int N)
{
    int wave = blockIdx.x * 4 + (threadIdx.x >> 6);
    int lane = threadIdx.x & 63;
    if (wave >= N) return;
    int start = row_ptr[wave], end = row_ptr[wave + 1];
    float d = dis[wave];
    float n2 = d * d;
    float2 v = ((const float2*)(ht + (size_t)wave * H))[lane];
    float2 b = ((const float2*)bias)[lane];
    float accx = v.x * n2 + b.x;
    float accy = v.y * n2 + b.y;
    for (int e = start; e < end; ++e) {
        float2 ed = edge_data[e];
        int s = __float_as_int(ed.x);
        float nrm = ed.y;
        float2 u = ((const float2*)(ht + (size_t)s * H))[lane];
        accx += u.x * nrm;
        accy += u.y * nrm;
    }
    ((float2*)(C + (size_t)wave * H))[lane] = make_float2(accx, accy);
}

// ---------------- BN reduce: per-channel sum & sumsq -------------------------
__global__ __launch_bounds__(256) void bn_reduce_kernel(const float* __restrict__ C,
    float* __restrict__ stats, int N)
{
    __shared__ float ls[256];
    __shared__ float lq[256];
    int tx = threadIdx.x;
    int c = tx & 127, half = tx >> 7;
    int base = blockIdx.x * 256;
    float s = 0.f, q = 0.f;
    for (int r = half; r < 256; r += 2) {
        int gr = base + r;
        if (gr >= N) break;
        float v = C[(size_t)gr * H + c];
        s += v;
        q += v * v;
    }
    ls[tx] = s;
    lq[tx] = q;
    __syncthreads();
    if (half == 0) {
        atomicAdd(&stats[c], ls[tx] + ls[tx + 128]);
        atomicAdd(&stats[H + c], lq[tx] + lq[tx + 128]);
    }
}

// ---------------- BN finalize: scale/shift from stats ------------------------
__global__ void bn_finalize_kernel(float* __restrict__ stats,
    const float* __restrict__ gamma, const float* __restrict__ beta, float invN)
{
    int c = threadIdx.x;  // 128 threads
    float mean = stats[c] * invN;
    float var = stats[H + c] * invN - mean * mean;
    float inv = rsqrtf(var + BN_EPS);
    float sc = gamma[c] * inv;
    stats[2 * H + c] = sc;
    stats[3 * H + c] = beta[c] - mean * sc;
}

// ---------------- BN apply + relu + residual (in-place into A) ---------------
__global__ __launch_bounds__(256) void bn_apply_kernel(const float* __restrict__ C,
    const float* __restrict__ stats, float* __restrict__ A, int N, int relu)
{
    int i = blockIdx.x * 256 + threadIdx.x;
    int node = i >> 5;
    if (node >= N) return;
    int c4 = i & 31;
    float4 v = ((const float4*)C)[i];
    float4 sc = ((const float4*)(stats + 2 * H))[c4];
    float4 sh = ((const float4*)(stats + 3 * H))[c4];
    float4 r = ((const float4*)A)[i];
    float4 o;
    o.x = v.x * sc.x + sh.x;
    o.y = v.y * sc.y + sh.y;
    o.z = v.z * sc.z + sh.z;
    o.w = v.w * sc.w + sh.w;
    if (relu) {
        o.x = fmaxf(o.x, 0.f);
        o.y = fmaxf(o.y, 0.f);
        o.z = fmaxf(o.z, 0.f);
        o.w = fmaxf(o.w, 0.f);
    }
    o.x += r.x;
    o.y += r.y;
    o.z += r.z;
    o.w += r.w;
    ((float4*)A)[i] = o;
}

// ---------------- mean-pool: segmented reduction over sorted batch_idx -------
#define POOL_ROWS 64
__global__ __launch_bounds__(128) void pool_kernel(const float* __restrict__ A,
    const int* __restrict__ batch, float* __restrict__ pooled,
    float* __restrict__ counts, int N)
{
    int c = threadIdx.x;
    int base = blockIdx.x * POOL_ROWS;
    int end = base + POOL_ROWS;
    if (end > N) end = N;
    if (base >= N) return;
    int curg = batch[base];
    int runStart = base;
    float acc = 0.f;
    for (int r = base; r < end; ++r) {
        int g = batch[r];
        if (g != curg) {
            atomicAdd(&pooled[(size_t)curg * H + c], acc);
            if (c == 0) atomicAdd(&counts[curg], (float)(r - runStart));
            curg = g;
            acc = 0.f;
            runStart = r;
        }
        acc += A[(size_t)r * H + c];
    }
    atomicAdd(&pooled[(size_t)curg * H + c], acc);
    if (c == 0) atomicAdd(&counts[curg], (float)(end - runStart));
}

// ---------------- final: sigmoid(mean . linW + b) ----------------------------
__global__ __launch_bounds__(256) void final_kernel(const float* __restrict__ pooled,
    const float* __restrict__ counts, const float* __restrict__ linW,
    const float* __restrict__ linb, float* __restrict__ out, int G)
{
    int g = blockIdx.x * 4 + (threadIdx.x >> 6);
    int lane = threadIdx.x & 63;
    if (g >= G) return;
    float2 p = ((const float2*)(pooled + (size_t)g * H))[lane];
    float2 w = ((const float2*)linW)[lane];
    float part = p.x * w.x + p.y * w.y;
#pragma unroll
    for (int off = 32; off > 0; off >>= 1)
        part += __shfl_down(part, off, 64);
    if (lane == 0) {
        float cnt = fmaxf(counts[g], 1.0f);
        float z = part / cnt + linb[0];
        out[g] = 1.0f / (1.0f + expf(-z));
    }
}

static inline size_t align4(size_t x) { return (x + 3) & ~(size_t)3; }  // 16B align (in floats)

extern "C" void kernel_launch(void* const* d_in, const int* in_sizes, int n_in,
                              void* d_out, int out_size, void* d_ws, size_t ws_size,
                              hipStream_t stream)
{
    const int* x = (const int*)d_in[0];
    const int* ei = (const int*)d_in[1];
    const int* batch = (const int*)d_in[2];
    const float* table = (const float*)d_in[3];
    const float* convW = (const float*)d_in[4];
    const float* convB = (const float*)d_in[5];
    const float* gamma = (const float*)d_in[6];
    const float* beta = (const float*)d_in[7];
    const float* linW = (const float*)d_in[8];
    const float* linb = (const float*)d_in[9];
    float* out = (float*)d_out;

    int N = in_sizes[0] / 9;
    int E = in_sizes[1] / 2;
    int G = out_size;
    int L = in_sizes[4] / (H * H);
    const int* row = ei;
    const int* col = ei + E;
    int NB = (N + 255) / 256;  // blocks for scan (must be <= 512)

    float* ws = (float*)d_ws;
    size_t off = 0;
    // ---- zeroed region ----
    int* deg = (int*)(ws + off);        off = align4(off + N);
    int* cnt = (int*)(ws + off);        off = align4(off + N);
    float* pooled = ws + off;           off = align4(off + (size_t)G * H);
    float* counts = ws + off;           off = align4(off + G);
    float* stats = ws + off;            off = align4(off + (size_t)L * 4 * H);
    size_t zero_bytes = off * sizeof(float);
    // ---- non-zeroed ----
    float* dis = ws + off;              off = align4(off + N);
    int* row_ptr = (int*)(ws + off);    off = align4(off + N + 1);
    int* blockSums = (int*)(ws + off);  off = align4(off + 512);
    unsigned short* wt = (unsigned short*)(ws + off); off = align4(off + (size_t)L * H * H);  // L*2*H*H ushort
    float2* edge_data = (float2*)(ws + off); off = align4(off + (size_t)2 * E);
    float* A = ws + off;                off += (size_t)N * H;
    float* B = ws + off;                off += (size_t)N * H;
    float* C = ws + off;                off += (size_t)N * H;

    hipMemsetAsync(d_ws, 0, zero_bytes, stream);

    enc_kernel<<<(N * 128 + 255) / 256, 256, 0, stream>>>(x, table, A, N);
    deg_kernel<<<(E + 255) / 256, 256, 0, stream>>>(col, deg, E);
    dis_kernel<<<(N + 255) / 256, 256, 0, stream>>>(deg, dis, N);
    scan1_kernel<<<NB, 256, 0, stream>>>(deg, blockSums, N);
    scan2_kernel<<<1, 512, 0, stream>>>(blockSums, NB);
    scan3_kernel<<<NB, 256, 0, stream>>>(deg, blockSums, row_ptr, N, E);
    fill_kernel<<<(E + 255) / 256, 256, 0, stream>>>(row, col, row_ptr, cnt, dis, edge_data, E);
    wprep_kernel<<<L * 128, 128, 0, stream>>>(convW, wt, L);

    int gemmBlocks = (N + 127) / 128;
    for (int l = 0; l < L; ++l) {
        float* st = stats + (size_t)l * 4 * H;
        const unsigned short* wthi = wt + (size_t)l * 2 * H * H;
        gemm_mfma_kernel<<<gemmBlocks, 256, 0, stream>>>(A, wthi, B, N);
        agg_kernel<<<(N + 3) / 4, 256, 0, stream>>>(B, row_ptr, edge_data, dis,
                                                    convB + (size_t)l * H, C, N);
        bn_reduce_kernel<<<NB, 256, 0, stream>>>(C, st, N);
        bn_finalize_kernel<<<1, 128, 0, stream>>>(st, gamma + (size_t)l * H, beta + (size_t)l * H, 1.0f / (float)N);
        bn_apply_kernel<<<(N * 32 + 255) / 256, 256, 0, stream>>>(C, st, A, N, (l < L - 1) ? 1 : 0);
    }

    pool_kernel<<<(N + POOL_ROWS - 1) / POOL_ROWS, 128, 0, stream>>>(A, batch, pooled, counts, N);
    final_kernel<<<(G + 3) / 4, 256, 0, stream>>>(pooled, counts, linW, linb, out, G);
}

// Round 5
// 1038.090 us; speedup vs baseline: 3.8064x; 1.0738x over previous
//
#include <hip/hip_runtime.h>
#include <math.h>

#define H 128
#define BN_EPS 1e-5f

typedef float float4v __attribute__((ext_vector_type(4)));
typedef short short8v __attribute__((ext_vector_type(8)));
typedef unsigned short ushort4v __attribute__((ext_vector_type(4)));
typedef unsigned short ushort8v __attribute__((ext_vector_type(8)));

__device__ inline unsigned short bf16h(float x) {
    unsigned int u = __float_as_uint(x);
    return (unsigned short)((u + 0x7fffu + ((u >> 16) & 1u)) >> 16);
}
__device__ inline float bf16f(unsigned short h) {
    return __uint_as_float(((unsigned int)h) << 16);
}

// ---------------- Atom encoder: h[n][c] = sum_f table[x[n][f]+off[f]][c] ----
__global__ __launch_bounds__(256) void enc_kernel(const int* __restrict__ x,
    const float* __restrict__ table, float* __restrict__ h, int N)
{
    int idx = blockIdx.x * 256 + threadIdx.x;
    int node = idx >> 7;
    if (node >= N) return;
    int c = idx & 127;
    const int offs[9] = {0, 119, 123, 135, 147, 157, 163, 169, 171};
    const int* xr = x + node * 9;
    float s = 0.f;
#pragma unroll
    for (int f = 0; f < 9; ++f)
        s += table[(size_t)(xr[f] + offs[f]) * H + c];
    h[idx] = s;
}

// ---------------- degree (in-degree over col), int atomics -------------------
__global__ __launch_bounds__(256) void deg_kernel(const int* __restrict__ col,
                                                  int* __restrict__ deg, int E)
{
    int e = blockIdx.x * 256 + threadIdx.x;
    if (e < E) atomicAdd(&deg[col[e]], 1);
}

__global__ __launch_bounds__(256) void dis_kernel(const int* __restrict__ deg,
                                                  float* __restrict__ dis, int N)
{
    int i = blockIdx.x * 256 + threadIdx.x;
    if (i < N) dis[i] = rsqrtf((float)deg[i] + 1.0f);  // +1 = self loop
}

// ---------------- scan step 1: per-block sums of deg -------------------------
__global__ __launch_bounds__(256) void scan1_kernel(const int* __restrict__ deg,
    int* __restrict__ blockSums, int N)
{
    __shared__ int s[256];
    int t = threadIdx.x;
    int g = blockIdx.x * 256 + t;
    s[t] = (g < N) ? deg[g] : 0;
    __syncthreads();
#pragma unroll
    for (int off = 128; off > 0; off >>= 1) {
        if (t < off) s[t] += s[t + off];
        __syncthreads();
    }
    if (t == 0) blockSums[blockIdx.x] = s[0];
}

// ---------------- scan step 2: exclusive scan of block sums (<=512) ----------
__global__ __launch_bounds__(512) void scan2_kernel(int* __restrict__ blockSums, int NB)
{
    __shared__ int s[512];
    int t = threadIdx.x;
    int own = (t < NB) ? blockSums[t] : 0;
    s[t] = own;
    __syncthreads();
    for (int off = 1; off < 512; off <<= 1) {
        int v = (t >= off) ? s[t - off] : 0;
        __syncthreads();
        s[t] += v;
        __syncthreads();
    }
    if (t < NB) blockSums[t] = s[t] - own;  // exclusive
}

// ---------------- scan step 3: final row_ptr ---------------------------------
__global__ __launch_bounds__(256) void scan3_kernel(const int* __restrict__ deg,
    const int* __restrict__ blockOff, int* __restrict__ row_ptr, int N, int E)
{
    __shared__ int s[256];
    int t = threadIdx.x;
    int g = blockIdx.x * 256 + t;
    int own = (g < N) ? deg[g] : 0;
    s[t] = own;
    __syncthreads();
    for (int off = 1; off < 256; off <<= 1) {
        int v = (t >= off) ? s[t - off] : 0;
        __syncthreads();
        s[t] += v;
        __syncthreads();
    }
    if (g < N) row_ptr[g] = blockOff[blockIdx.x] + s[t] - own;
    if (g == N - 1) row_ptr[N] = E;
}

// ---------------- fill CSR: edge_data[pos] = {src, norm} ---------------------
__global__ __launch_bounds__(256) void fill_kernel(const int* __restrict__ row,
    const int* __restrict__ col, const int* __restrict__ row_ptr,
    int* __restrict__ cnt, const float* __restrict__ dis,
    float2* __restrict__ edge_data, int E)
{
    int e = blockIdx.x * 256 + threadIdx.x;
    if (e >= E) return;
    int r = row[e], c = col[e];
    int pos = row_ptr[c] + atomicAdd(&cnt[c], 1);
    edge_data[pos] = make_float2(__int_as_float(r), dis[r] * dis[c]);
}

// ---------------- W prep: Wt_hi/lo[l][n][k] = bf16split(W[l][k][n]) ----------
__global__ __launch_bounds__(128) void wprep_kernel(const float* __restrict__ W,
    unsigned short* __restrict__ wt, int L)
{
    int b = blockIdx.x;
    int l = b >> 7, k = b & 127;
    int n = threadIdx.x;
    float x = W[(size_t)l * H * H + (size_t)k * H + n];
    unsigned short hi = bf16h(x);
    unsigned short lo = bf16h(x - bf16f(hi));
    unsigned short* base = wt + (size_t)l * 2 * H * H;
    base[(size_t)n * H + k] = hi;                       // hi block [n][k]
    base[(size_t)H * H + (size_t)n * H + k] = lo;       // lo block [n][k]
}

// ---------------- MFMA GEMM: out[N][128] = A[N][128] @ W[128][128] -----------
#define LSTR 40  // LDS row stride in shorts (padded from 32)
__global__ __launch_bounds__(256) void gemm_mfma_kernel(const float* __restrict__ A,
    const unsigned short* __restrict__ wthi, float* __restrict__ out, int N)
{
    __shared__ unsigned short Ah[128 * LSTR];
    __shared__ unsigned short Al[128 * LSTR];
    __shared__ unsigned short Bh[128 * LSTR];
    __shared__ unsigned short Bl[128 * LSTR];

    const unsigned short* wtlo = wthi + H * H;
    const int tx = threadIdx.x;
    const int rowBase = blockIdx.x * 128;
    const int lane = tx & 63;
    const int w = tx >> 6;
    const int rw = (w & 1) * 64;
    const int cw = (w >> 1) * 64;
    const int mrow = lane & 15;
    const int quad = lane >> 4;

    float4v acc[4][4];
#pragma unroll
    for (int i = 0; i < 4; ++i)
#pragma unroll
        for (int j = 0; j < 4; ++j)
            acc[i][j] = (float4v)(0.f);

    const float4* A4 = (const float4*)A;

    for (int kk = 0; kk < 128; kk += 32) {
        __syncthreads();
#pragma unroll
        for (int i = 0; i < 4; ++i) {
            int idx = i * 256 + tx;          // 0..1023
            int r = idx >> 3;                // 0..127
            int f4 = idx & 7;                // float4 within 32-col chunk
            int gr = rowBase + r;
            float4 v = (gr < N) ? A4[(size_t)gr * 32 + (kk >> 2) + f4]
                                : make_float4(0.f, 0.f, 0.f, 0.f);
            unsigned short h0 = bf16h(v.x), h1 = bf16h(v.y), h2 = bf16h(v.z), h3 = bf16h(v.w);
            ushort4v hv = {h0, h1, h2, h3};
            ushort4v lv = {bf16h(v.x - bf16f(h0)), bf16h(v.y - bf16f(h1)),
                           bf16h(v.z - bf16f(h2)), bf16h(v.w - bf16f(h3))};
            *(ushort4v*)&Ah[r * LSTR + f4 * 4] = hv;
            *(ushort4v*)&Al[r * LSTR + f4 * 4] = lv;
        }
#pragma unroll
        for (int i = 0; i < 2; ++i) {
            int idx = i * 256 + tx;          // 0..511
            int n = idx >> 2;                // 0..127
            int q = idx & 3;                 // 8-short segment
            *(ushort8v*)&Bh[n * LSTR + q * 8] = *(const ushort8v*)&wthi[(size_t)n * H + kk + q * 8];
            *(ushort8v*)&Bl[n * LSTR + q * 8] = *(const ushort8v*)&wtlo[(size_t)n * H + kk + q * 8];
        }
        __syncthreads();

        short8v ah[4], al[4], bh[4], bl[4];
#pragma unroll
        for (int t = 0; t < 4; ++t) {
            ah[t] = *(const short8v*)&Ah[(rw + t * 16 + mrow) * LSTR + quad * 8];
            al[t] = *(const short8v*)&Al[(rw + t * 16 + mrow) * LSTR + quad * 8];
            bh[t] = *(const short8v*)&Bh[(cw + t * 16 + mrow) * LSTR + quad * 8];
            bl[t] = *(const short8v*)&Bl[(cw + t * 16 + mrow) * LSTR + quad * 8];
        }
#pragma unroll
        for (int ti = 0; ti < 4; ++ti)
#pragma unroll
            for (int tj = 0; tj < 4; ++tj) {
                acc[ti][tj] = __builtin_amdgcn_mfma_f32_16x16x32_bf16(ah[ti], bh[tj], acc[ti][tj], 0, 0, 0);
                acc[ti][tj] = __builtin_amdgcn_mfma_f32_16x16x32_bf16(ah[ti], bl[tj], acc[ti][tj], 0, 0, 0);
                acc[ti][tj] = __builtin_amdgcn_mfma_f32_16x16x32_bf16(al[ti], bh[tj], acc[ti][tj], 0, 0, 0);
            }
    }

#pragma unroll
    for (int ti = 0; ti < 4; ++ti) {
#pragma unroll
        for (int i = 0; i < 4; ++i) {
            int gr = rowBase + rw + ti * 16 + quad * 4 + i;
            if (gr < N) {
#pragma unroll
                for (int tj = 0; tj < 4; ++tj)
                    out[(size_t)gr * H + cw + tj * 16 + mrow] = acc[ti][tj][i];
            }
        }
    }
}

// ---------------- CSR aggregation, fused self-loop + bias --------------------
// one wave per node; lane-parallel edge metadata preload + shfl broadcast;
// 4-way unrolled independent gathers for MLP.
__global__ __launch_bounds__(256) void agg_kernel(const float* __restrict__ ht,
    const int* __restrict__ row_ptr, const float2* __restrict__ edge_data,
    const float* __restrict__ dis, const float* __restrict__ bias,
    float* __restrict__ C, int N)
{
    int wave = blockIdx.x * 4 + (threadIdx.x >> 6);
    int lane = threadIdx.x & 63;
    if (wave >= N) return;
    int start = row_ptr[wave], end = row_ptr[wave + 1];
    int cnt = end - start;
    float d = dis[wave];
    float n2 = d * d;
    float2 v = ((const float2*)(ht + (size_t)wave * H))[lane];
    float2 b = ((const float2*)bias)[lane];
    float ax0 = v.x * n2 + b.x, ay0 = v.y * n2 + b.y;
    float ax1 = 0.f, ay1 = 0.f, ax2 = 0.f, ay2 = 0.f, ax3 = 0.f, ay3 = 0.f;

    int cmain = cnt > 64 ? 64 : cnt;
    float2 edl = (lane < cmain) ? edge_data[start + lane] : make_float2(0.f, 0.f);

    int j = 0;
    for (; j + 4 <= cmain; j += 4) {
        int s0 = __float_as_int(__shfl(edl.x, j, 64));
        float w0 = __shfl(edl.y, j, 64);
        int s1 = __float_as_int(__shfl(edl.x, j + 1, 64));
        float w1 = __shfl(edl.y, j + 1, 64);
        int s2 = __float_as_int(__shfl(edl.x, j + 2, 64));
        float w2 = __shfl(edl.y, j + 2, 64);
        int s3 = __float_as_int(__shfl(edl.x, j + 3, 64));
        float w3 = __shfl(edl.y, j + 3, 64);
        float2 u0 = ((const float2*)(ht + (size_t)s0 * H))[lane];
        float2 u1 = ((const float2*)(ht + (size_t)s1 * H))[lane];
        float2 u2 = ((const float2*)(ht + (size_t)s2 * H))[lane];
        float2 u3 = ((const float2*)(ht + (size_t)s3 * H))[lane];
        ax0 += u0.x * w0; ay0 += u0.y * w0;
        ax1 += u1.x * w1; ay1 += u1.y * w1;
        ax2 += u2.x * w2; ay2 += u2.y * w2;
        ax3 += u3.x * w3; ay3 += u3.y * w3;
    }
    for (; j < cmain; ++j) {
        int s0 = __float_as_int(__shfl(edl.x, j, 64));
        float w0 = __shfl(edl.y, j, 64);
        float2 u0 = ((const float2*)(ht + (size_t)s0 * H))[lane];
        ax0 += u0.x * w0; ay0 += u0.y * w0;
    }
    for (int e = start + 64; e < end; ++e) {  // rare: degree > 64
        float2 ed = edge_data[e];
        int s = __float_as_int(ed.x);
        float2 u = ((const float2*)(ht + (size_t)s * H))[lane];
        ax0 += u.x * ed.y; ay0 += u.y * ed.y;
    }
    float ox = (ax0 + ax1) + (ax2 + ax3);
    float oy = (ay0 + ay1) + (ay2 + ay3);
    ((float2*)(C + (size_t)wave * H))[lane] = make_float2(ox, oy);
}

// ---------------- BN reduce: per-channel sum & sumsq -------------------------
__global__ __launch_bounds__(256) void bn_reduce_kernel(const float* __restrict__ C,
    float* __restrict__ stats, int N)
{
    __shared__ float ls[256];
    __shared__ float lq[256];
    int tx = threadIdx.x;
    int c = tx & 127, half = tx >> 7;
    int base = blockIdx.x * 256;
    float s = 0.f, q = 0.f;
    for (int r = half; r < 256; r += 2) {
        int gr = base + r;
        if (gr >= N) break;
        float v = C[(size_t)gr * H + c];
        s += v;
        q += v * v;
    }
    ls[tx] = s;
    lq[tx] = q;
    __syncthreads();
    if (half == 0) {
        atomicAdd(&stats[c], ls[tx] + ls[tx + 128]);
        atomicAdd(&stats[H + c], lq[tx] + lq[tx + 128]);
    }
}

// ---------------- BN finalize: scale/shift from stats ------------------------
__global__ void bn_finalize_kernel(float* __restrict__ stats,
    const float* __restrict__ gamma, const float* __restrict__ beta, float invN)
{
    int c = threadIdx.x;  // 128 threads
    float mean = stats[c] * invN;
    float var = stats[H + c] * invN - mean * mean;
    float inv = rsqrtf(var + BN_EPS);
    float sc = gamma[c] * inv;
    stats[2 * H + c] = sc;
    stats[3 * H + c] = beta[c] - mean * sc;
}

// ---------------- BN apply + relu + residual (in-place into A) ---------------
__global__ __launch_bounds__(256) void bn_apply_kernel(const float* __restrict__ C,
    const float* __restrict__ stats, float* __restrict__ A, int N, int relu)
{
    int i = blockIdx.x * 256 + threadIdx.x;
    int node = i >> 5;
    if (node >= N) return;
    int c4 = i & 31;
    float4 v = ((const float4*)C)[i];
    float4 sc = ((const float4*)(stats + 2 * H))[c4];
    float4 sh = ((const float4*)(stats + 3 * H))[c4];
    float4 r = ((const float4*)A)[i];
    float4 o;
    o.x = v.x * sc.x + sh.x;
    o.y = v.y * sc.y + sh.y;
    o.z = v.z * sc.z + sh.z;
    o.w = v.w * sc.w + sh.w;
    if (relu) {
        o.x = fmaxf(o.x, 0.f);
        o.y = fmaxf(o.y, 0.f);
        o.z = fmaxf(o.z, 0.f);
        o.w = fmaxf(o.w, 0.f);
    }
    o.x += r.x;
    o.y += r.y;
    o.z += r.z;
    o.w += r.w;
    ((float4*)A)[i] = o;
}

// ---------------- mean-pool: segmented reduction over sorted batch_idx -------
#define POOL_ROWS 64
__global__ __launch_bounds__(128) void pool_kernel(const float* __restrict__ A,
    const int* __restrict__ batch, float* __restrict__ pooled,
    float* __restrict__ counts, int N)
{
    int c = threadIdx.x;
    int base = blockIdx.x * POOL_ROWS;
    int end = base + POOL_ROWS;
    if (end > N) end = N;
    if (base >= N) return;
    int curg = batch[base];
    int runStart = base;
    float acc = 0.f;
    for (int r = base; r < end; ++r) {
        int g = batch[r];
        if (g != curg) {
            atomicAdd(&pooled[(size_t)curg * H + c], acc);
            if (c == 0) atomicAdd(&counts[curg], (float)(r - runStart));
            curg = g;
            acc = 0.f;
            runStart = r;
        }
        acc += A[(size_t)r * H + c];
    }
    atomicAdd(&pooled[(size_t)curg * H + c], acc);
    if (c == 0) atomicAdd(&counts[curg], (float)(end - runStart));
}

// ---------------- final: sigmoid(mean . linW + b) ----------------------------
__global__ __launch_bounds__(256) void final_kernel(const float* __restrict__ pooled,
    const float* __restrict__ counts, const float* __restrict__ linW,
    const float* __restrict__ linb, float* __restrict__ out, int G)
{
    int g = blockIdx.x * 4 + (threadIdx.x >> 6);
    int lane = threadIdx.x & 63;
    if (g >= G) return;
    float2 p = ((const float2*)(pooled + (size_t)g * H))[lane];
    float2 w = ((const float2*)linW)[lane];
    float part = p.x * w.x + p.y * w.y;
#pragma unroll
    for (int off = 32; off > 0; off >>= 1)
        part += __shfl_down(part, off, 64);
    if (lane == 0) {
        float cnt = fmaxf(counts[g], 1.0f);
        float z = part / cnt + linb[0];
        out[g] = 1.0f / (1.0f + expf(-z));
    }
}

static inline size_t align4(size_t x) { return (x + 3) & ~(size_t)3; }  // 16B align (in floats)

extern "C" void kernel_launch(void* const* d_in, const int* in_sizes, int n_in,
                              void* d_out, int out_size, void* d_ws, size_t ws_size,
                              hipStream_t stream)
{
    const int* x = (const int*)d_in[0];
    const int* ei = (const int*)d_in[1];
    const int* batch = (const int*)d_in[2];
    const float* table = (const float*)d_in[3];
    const float* convW = (const float*)d_in[4];
    const float* convB = (const float*)d_in[5];
    const float* gamma = (const float*)d_in[6];
    const float* beta = (const float*)d_in[7];
    const float* linW = (const float*)d_in[8];
    const float* linb = (const float*)d_in[9];
    float* out = (float*)d_out;

    int N = in_sizes[0] / 9;
    int E = in_sizes[1] / 2;
    int G = out_size;
    int L = in_sizes[4] / (H * H);
    const int* row = ei;
    const int* col = ei + E;
    int NB = (N + 255) / 256;  // blocks for scan (must be <= 512)

    float* ws = (float*)d_ws;
    size_t off = 0;
    // ---- zeroed region ----
    int* deg = (int*)(ws + off);        off = align4(off + N);
    int* cnt = (int*)(ws + off);        off = align4(off + N);
    float* pooled = ws + off;           off = align4(off + (size_t)G * H);
    float* counts = ws + off;           off = align4(off + G);
    float* stats = ws + off;            off = align4(off + (size_t)L * 4 * H);
    size_t zero_bytes = off * sizeof(float);
    // ---- non-zeroed ----
    float* dis = ws + off;              off = align4(off + N);
    int* row_ptr = (int*)(ws + off);    off = align4(off + N + 1);
    int* blockSums = (int*)(ws + off);  off = align4(off + 512);
    unsigned short* wt = (unsigned short*)(ws + off); off = align4(off + (size_t)L * H * H);  // L*2*H*H ushort
    float2* edge_data = (float2*)(ws + off); off = align4(off + (size_t)2 * E);
    float* A = ws + off;                off += (size_t)N * H;
    float* B = ws + off;                off += (size_t)N * H;
    float* C = ws + off;                off += (size_t)N * H;

    hipMemsetAsync(d_ws, 0, zero_bytes, stream);

    enc_kernel<<<(N * 128 + 255) / 256, 256, 0, stream>>>(x, table, A, N);
    deg_kernel<<<(E + 255) / 256, 256, 0, stream>>>(col, deg, E);
    dis_kernel<<<(N + 255) / 256, 256, 0, stream>>>(deg, dis, N);
    scan1_kernel<<<NB, 256, 0, stream>>>(deg, blockSums, N);
    scan2_kernel<<<1, 512, 0, stream>>>(blockSums, NB);
    scan3_kernel<<<NB, 256, 0, stream>>>(deg, blockSums, row_ptr, N, E);
    fill_kernel<<<(E + 255) / 256, 256, 0, stream>>>(row, col, row_ptr, cnt, dis, edge_data, E);
    wprep_kernel<<<L * 128, 128, 0, stream>>>(convW, wt, L);

    int gemmBlocks = (N + 127) / 128;
    for (int l = 0; l < L; ++l) {
        float* st = stats + (size_t)l * 4 * H;
        const unsigned short* wthi = wt + (size_t)l * 2 * H * H;
        gemm_mfma_kernel<<<gemmBlocks, 256, 0, stream>>>(A, wthi, B, N);
        agg_kernel<<<(N + 3) / 4, 256, 0, stream>>>(B, row_ptr, edge_data, dis,
                                                    convB + (size_t)l * H, C, N);
        bn_reduce_kernel<<<NB, 256, 0, stream>>>(C, st, N);
        bn_finalize_kernel<<<1, 128, 0, stream>>>(st, gamma + (size_t)l * H, beta + (size_t)l * H, 1.0f / (float)N);
        bn_apply_kernel<<<(N * 32 + 255) / 256, 256, 0, stream>>>(C, st, A, N, (l < L - 1) ? 1 : 0);
    }

    pool_kernel<<<(N + POOL_ROWS - 1) / POOL_ROWS, 128, 0, stream>>>(A, batch, pooled, counts, N);
    final_kernel<<<(G + 3) / 4, 256, 0, stream>>>(pooled, counts, linW, linb, out, G);
}

// Round 6
// 922.759 us; speedup vs baseline: 4.2822x; 1.1250x over previous
//
#include <hip/hip_runtime.h>
#include <math.h>

#define H 128
#define BN_EPS 1e-5f

typedef float float4v __attribute__((ext_vector_type(4)));
typedef short short8v __attribute__((ext_vector_type(8)));
typedef unsigned short ushort4v __attribute__((ext_vector_type(4)));
typedef unsigned short ushort8v __attribute__((ext_vector_type(8)));

__device__ inline unsigned short bf16h(float x) {
    unsigned int u = __float_as_uint(x);
    return (unsigned short)((u + 0x7fffu + ((u >> 16) & 1u)) >> 16);
}
__device__ inline float bf16f(unsigned short h) {
    return __uint_as_float(((unsigned int)h) << 16);
}

// ---------------- Atom encoder: h[n][c] = sum_f table[x[n][f]+off[f]][c] ----
__global__ __launch_bounds__(256) void enc_kernel(const int* __restrict__ x,
    const float* __restrict__ table, float* __restrict__ h, int N)
{
    int idx = blockIdx.x * 256 + threadIdx.x;
    int node = idx >> 7;
    if (node >= N) return;
    int c = idx & 127;
    const int offs[9] = {0, 119, 123, 135, 147, 157, 163, 169, 171};
    const int* xr = x + node * 9;
    float s = 0.f;
#pragma unroll
    for (int f = 0; f < 9; ++f)
        s += table[(size_t)(xr[f] + offs[f]) * H + c];
    h[idx] = s;
}

// ---------------- degree (in-degree over col), int atomics -------------------
__global__ __launch_bounds__(256) void deg_kernel(const int* __restrict__ col,
                                                  int* __restrict__ deg, int E)
{
    int e = blockIdx.x * 256 + threadIdx.x;
    if (e < E) atomicAdd(&deg[col[e]], 1);
}

__global__ __launch_bounds__(256) void dis_kernel(const int* __restrict__ deg,
                                                  float* __restrict__ dis, int N)
{
    int i = blockIdx.x * 256 + threadIdx.x;
    if (i < N) dis[i] = rsqrtf((float)deg[i] + 1.0f);  // +1 = self loop
}

// ---------------- scan step 1: per-block sums of deg -------------------------
__global__ __launch_bounds__(256) void scan1_kernel(const int* __restrict__ deg,
    int* __restrict__ blockSums, int N)
{
    __shared__ int s[256];
    int t = threadIdx.x;
    int g = blockIdx.x * 256 + t;
    s[t] = (g < N) ? deg[g] : 0;
    __syncthreads();
#pragma unroll
    for (int off = 128; off > 0; off >>= 1) {
        if (t < off) s[t] += s[t + off];
        __syncthreads();
    }
    if (t == 0) blockSums[blockIdx.x] = s[0];
}

// ---------------- scan step 2: exclusive scan of block sums (<=512) ----------
__global__ __launch_bounds__(512) void scan2_kernel(int* __restrict__ blockSums, int NB)
{
    __shared__ int s[512];
    int t = threadIdx.x;
    int own = (t < NB) ? blockSums[t] : 0;
    s[t] = own;
    __syncthreads();
    for (int off = 1; off < 512; off <<= 1) {
        int v = (t >= off) ? s[t - off] : 0;
        __syncthreads();
        s[t] += v;
        __syncthreads();
    }
    if (t < NB) blockSums[t] = s[t] - own;  // exclusive
}

// ---------------- scan step 3: final row_ptr ---------------------------------
__global__ __launch_bounds__(256) void scan3_kernel(const int* __restrict__ deg,
    const int* __restrict__ blockOff, int* __restrict__ row_ptr, int N, int E)
{
    __shared__ int s[256];
    int t = threadIdx.x;
    int g = blockIdx.x * 256 + t;
    int own = (g < N) ? deg[g] : 0;
    s[t] = own;
    __syncthreads();
    for (int off = 1; off < 256; off <<= 1) {
        int v = (t >= off) ? s[t - off] : 0;
        __syncthreads();
        s[t] += v;
        __syncthreads();
    }
    if (g < N) row_ptr[g] = blockOff[blockIdx.x] + s[t] - own;
    if (g == N - 1) row_ptr[N] = E;
}

// ---------------- fill CSR: edge_data[pos] = {src, norm} ---------------------
__global__ __launch_bounds__(256) void fill_kernel(const int* __restrict__ row,
    const int* __restrict__ col, const int* __restrict__ row_ptr,
    int* __restrict__ cnt, const float* __restrict__ dis,
    float2* __restrict__ edge_data, int E)
{
    int e = blockIdx.x * 256 + threadIdx.x;
    if (e >= E) return;
    int r = row[e], c = col[e];
    int pos = row_ptr[c] + atomicAdd(&cnt[c], 1);
    edge_data[pos] = make_float2(__int_as_float(r), dis[r] * dis[c]);
}

// ---------------- W prep: Wt_hi/lo[l][n][k] = bf16split(W[l][k][n]) ----------
__global__ __launch_bounds__(128) void wprep_kernel(const float* __restrict__ W,
    unsigned short* __restrict__ wt, int L)
{
    int b = blockIdx.x;
    int l = b >> 7, k = b & 127;
    int n = threadIdx.x;
    float x = W[(size_t)l * H * H + (size_t)k * H + n];
    unsigned short hi = bf16h(x);
    unsigned short lo = bf16h(x - bf16f(hi));
    unsigned short* base = wt + (size_t)l * 2 * H * H;
    base[(size_t)n * H + k] = hi;                       // hi block [n][k]
    base[(size_t)H * H + (size_t)n * H + k] = lo;       // lo block [n][k]
}

// ---------------- MFMA GEMM: out[N][128] = A[N][128] @ W[128][128] -----------
// split-bf16 inputs, bf16 OUTPUT (consumed only by agg gathers)
#define LSTR 40  // LDS row stride in shorts (padded from 32)
__global__ __launch_bounds__(256) void gemm_mfma_kernel(const float* __restrict__ A,
    const unsigned short* __restrict__ wthi, unsigned short* __restrict__ out, int N)
{
    __shared__ unsigned short Ah[128 * LSTR];
    __shared__ unsigned short Al[128 * LSTR];
    __shared__ unsigned short Bh[128 * LSTR];
    __shared__ unsigned short Bl[128 * LSTR];

    const unsigned short* wtlo = wthi + H * H;
    const int tx = threadIdx.x;
    const int rowBase = blockIdx.x * 128;
    const int lane = tx & 63;
    const int w = tx >> 6;
    const int rw = (w & 1) * 64;
    const int cw = (w >> 1) * 64;
    const int mrow = lane & 15;
    const int quad = lane >> 4;

    float4v acc[4][4];
#pragma unroll
    for (int i = 0; i < 4; ++i)
#pragma unroll
        for (int j = 0; j < 4; ++j)
            acc[i][j] = (float4v)(0.f);

    const float4* A4 = (const float4*)A;

    for (int kk = 0; kk < 128; kk += 32) {
        __syncthreads();
#pragma unroll
        for (int i = 0; i < 4; ++i) {
            int idx = i * 256 + tx;          // 0..1023
            int r = idx >> 3;                // 0..127
            int f4 = idx & 7;                // float4 within 32-col chunk
            int gr = rowBase + r;
            float4 v = (gr < N) ? A4[(size_t)gr * 32 + (kk >> 2) + f4]
                                : make_float4(0.f, 0.f, 0.f, 0.f);
            unsigned short h0 = bf16h(v.x), h1 = bf16h(v.y), h2 = bf16h(v.z), h3 = bf16h(v.w);
            ushort4v hv = {h0, h1, h2, h3};
            ushort4v lv = {bf16h(v.x - bf16f(h0)), bf16h(v.y - bf16f(h1)),
                           bf16h(v.z - bf16f(h2)), bf16h(v.w - bf16f(h3))};
            *(ushort4v*)&Ah[r * LSTR + f4 * 4] = hv;
            *(ushort4v*)&Al[r * LSTR + f4 * 4] = lv;
        }
#pragma unroll
        for (int i = 0; i < 2; ++i) {
            int idx = i * 256 + tx;          // 0..511
            int n = idx >> 2;                // 0..127
            int q = idx & 3;                 // 8-short segment
            *(ushort8v*)&Bh[n * LSTR + q * 8] = *(const ushort8v*)&wthi[(size_t)n * H + kk + q * 8];
            *(ushort8v*)&Bl[n * LSTR + q * 8] = *(const ushort8v*)&wtlo[(size_t)n * H + kk + q * 8];
        }
        __syncthreads();

        short8v ah[4], al[4], bh[4], bl[4];
#pragma unroll
        for (int t = 0; t < 4; ++t) {
            ah[t] = *(const short8v*)&Ah[(rw + t * 16 + mrow) * LSTR + quad * 8];
            al[t] = *(const short8v*)&Al[(rw + t * 16 + mrow) * LSTR + quad * 8];
            bh[t] = *(const short8v*)&Bh[(cw + t * 16 + mrow) * LSTR + quad * 8];
            bl[t] = *(const short8v*)&Bl[(cw + t * 16 + mrow) * LSTR + quad * 8];
        }
#pragma unroll
        for (int ti = 0; ti < 4; ++ti)
#pragma unroll
            for (int tj = 0; tj < 4; ++tj) {
                acc[ti][tj] = __builtin_amdgcn_mfma_f32_16x16x32_bf16(ah[ti], bh[tj], acc[ti][tj], 0, 0, 0);
                acc[ti][tj] = __builtin_amdgcn_mfma_f32_16x16x32_bf16(ah[ti], bl[tj], acc[ti][tj], 0, 0, 0);
                acc[ti][tj] = __builtin_amdgcn_mfma_f32_16x16x32_bf16(al[ti], bh[tj], acc[ti][tj], 0, 0, 0);
            }
    }

#pragma unroll
    for (int ti = 0; ti < 4; ++ti) {
#pragma unroll
        for (int i = 0; i < 4; ++i) {
            int gr = rowBase + rw + ti * 16 + quad * 4 + i;
            if (gr < N) {
#pragma unroll
                for (int tj = 0; tj < 4; ++tj)
                    out[(size_t)gr * H + cw + tj * 16 + mrow] = bf16h(acc[ti][tj][i]);
            }
        }
    }
}

// ---------------- CSR aggregation (bf16 ht), fused self-loop + bias ----------
// one wave per node; lane owns 2 channels (1 dword bf16x2 per gather);
// edge metadata preloaded + shfl broadcast; 4-way unrolled gathers.
__global__ __launch_bounds__(256) void agg_kernel(const unsigned short* __restrict__ ht,
    const int* __restrict__ row_ptr, const float2* __restrict__ edge_data,
    const float* __restrict__ dis, const float* __restrict__ bias,
    float* __restrict__ C, int N)
{
    int wave = blockIdx.x * 4 + (threadIdx.x >> 6);
    int lane = threadIdx.x & 63;
    if (wave >= N) return;
    int start = row_ptr[wave], end = row_ptr[wave + 1];
    int cnt = end - start;
    float d = dis[wave];
    float n2 = d * d;
    unsigned int uv = ((const unsigned int*)(ht + (size_t)wave * H))[lane];
    float vx = bf16f((unsigned short)(uv & 0xffffu));
    float vy = bf16f((unsigned short)(uv >> 16));
    float2 b = ((const float2*)bias)[lane];
    float ax0 = vx * n2 + b.x, ay0 = vy * n2 + b.y;
    float ax1 = 0.f, ay1 = 0.f, ax2 = 0.f, ay2 = 0.f, ax3 = 0.f, ay3 = 0.f;

    int cmain = cnt > 64 ? 64 : cnt;
    float2 edl = (lane < cmain) ? edge_data[start + lane] : make_float2(0.f, 0.f);

    int j = 0;
    for (; j + 4 <= cmain; j += 4) {
        int s0 = __float_as_int(__shfl(edl.x, j, 64));
        float w0 = __shfl(edl.y, j, 64);
        int s1 = __float_as_int(__shfl(edl.x, j + 1, 64));
        float w1 = __shfl(edl.y, j + 1, 64);
        int s2 = __float_as_int(__shfl(edl.x, j + 2, 64));
        float w2 = __shfl(edl.y, j + 2, 64);
        int s3 = __float_as_int(__shfl(edl.x, j + 3, 64));
        float w3 = __shfl(edl.y, j + 3, 64);
        unsigned int u0 = ((const unsigned int*)(ht + (size_t)s0 * H))[lane];
        unsigned int u1 = ((const unsigned int*)(ht + (size_t)s1 * H))[lane];
        unsigned int u2 = ((const unsigned int*)(ht + (size_t)s2 * H))[lane];
        unsigned int u3 = ((const unsigned int*)(ht + (size_t)s3 * H))[lane];
        ax0 += bf16f((unsigned short)(u0 & 0xffffu)) * w0;
        ay0 += bf16f((unsigned short)(u0 >> 16)) * w0;
        ax1 += bf16f((unsigned short)(u1 & 0xffffu)) * w1;
        ay1 += bf16f((unsigned short)(u1 >> 16)) * w1;
        ax2 += bf16f((unsigned short)(u2 & 0xffffu)) * w2;
        ay2 += bf16f((unsigned short)(u2 >> 16)) * w2;
        ax3 += bf16f((unsigned short)(u3 & 0xffffu)) * w3;
        ay3 += bf16f((unsigned short)(u3 >> 16)) * w3;
    }
    for (; j < cmain; ++j) {
        int s0 = __float_as_int(__shfl(edl.x, j, 64));
        float w0 = __shfl(edl.y, j, 64);
        unsigned int u0 = ((const unsigned int*)(ht + (size_t)s0 * H))[lane];
        ax0 += bf16f((unsigned short)(u0 & 0xffffu)) * w0;
        ay0 += bf16f((unsigned short)(u0 >> 16)) * w0;
    }
    for (int e = start + 64; e < end; ++e) {  // rare: degree > 64
        float2 ed = edge_data[e];
        int s = __float_as_int(ed.x);
        unsigned int u0 = ((const unsigned int*)(ht + (size_t)s * H))[lane];
        ax0 += bf16f((unsigned short)(u0 & 0xffffu)) * ed.y;
        ay0 += bf16f((unsigned short)(u0 >> 16)) * ed.y;
    }
    float ox = (ax0 + ax1) + (ax2 + ax3);
    float oy = (ay0 + ay1) + (ay2 + ay3);
    ((float2*)(C + (size_t)wave * H))[lane] = make_float2(ox, oy);
}

// ---------------- BN reduce: per-channel sum & sumsq -------------------------
__global__ __launch_bounds__(256) void bn_reduce_kernel(const float* __restrict__ C,
    float* __restrict__ stats, int N)
{
    __shared__ float ls[256];
    __shared__ float lq[256];
    int tx = threadIdx.x;
    int c = tx & 127, half = tx >> 7;
    int base = blockIdx.x * 256;
    float s = 0.f, q = 0.f;
    for (int r = half; r < 256; r += 2) {
        int gr = base + r;
        if (gr >= N) break;
        float v = C[(size_t)gr * H + c];
        s += v;
        q += v * v;
    }
    ls[tx] = s;
    lq[tx] = q;
    __syncthreads();
    if (half == 0) {
        atomicAdd(&stats[c], ls[tx] + ls[tx + 128]);
        atomicAdd(&stats[H + c], lq[tx] + lq[tx + 128]);
    }
}

// ---------------- BN finalize: scale/shift from stats ------------------------
__global__ void bn_finalize_kernel(float* __restrict__ stats,
    const float* __restrict__ gamma, const float* __restrict__ beta, float invN)
{
    int c = threadIdx.x;  // 128 threads
    float mean = stats[c] * invN;
    float var = stats[H + c] * invN - mean * mean;
    float inv = rsqrtf(var + BN_EPS);
    float sc = gamma[c] * inv;
    stats[2 * H + c] = sc;
    stats[3 * H + c] = beta[c] - mean * sc;
}

// ---------------- BN apply + relu + residual (in-place into A) ---------------
__global__ __launch_bounds__(256) void bn_apply_kernel(const float* __restrict__ C,
    const float* __restrict__ stats, float* __restrict__ A, int N, int relu)
{
    int i = blockIdx.x * 256 + threadIdx.x;
    int node = i >> 5;
    if (node >= N) return;
    int c4 = i & 31;
    float4 v = ((const float4*)C)[i];
    float4 sc = ((const float4*)(stats + 2 * H))[c4];
    float4 sh = ((const float4*)(stats + 3 * H))[c4];
    float4 r = ((const float4*)A)[i];
    float4 o;
    o.x = v.x * sc.x + sh.x;
    o.y = v.y * sc.y + sh.y;
    o.z = v.z * sc.z + sh.z;
    o.w = v.w * sc.w + sh.w;
    if (relu) {
        o.x = fmaxf(o.x, 0.f);
        o.y = fmaxf(o.y, 0.f);
        o.z = fmaxf(o.z, 0.f);
        o.w = fmaxf(o.w, 0.f);
    }
    o.x += r.x;
    o.y += r.y;
    o.z += r.z;
    o.w += r.w;
    ((float4*)A)[i] = o;
}

// ---------------- mean-pool: segmented reduction over sorted batch_idx -------
#define POOL_ROWS 64
__global__ __launch_bounds__(128) void pool_kernel(const float* __restrict__ A,
    const int* __restrict__ batch, float* __restrict__ pooled,
    float* __restrict__ counts, int N)
{
    int c = threadIdx.x;
    int base = blockIdx.x * POOL_ROWS;
    int end = base + POOL_ROWS;
    if (end > N) end = N;
    if (base >= N) return;
    int curg = batch[base];
    int runStart = base;
    float acc = 0.f;
    for (int r = base; r < end; ++r) {
        int g = batch[r];
        if (g != curg) {
            atomicAdd(&pooled[(size_t)curg * H + c], acc);
            if (c == 0) atomicAdd(&counts[curg], (float)(r - runStart));
            curg = g;
            acc = 0.f;
            runStart = r;
        }
        acc += A[(size_t)r * H + c];
    }
    atomicAdd(&pooled[(size_t)curg * H + c], acc);
    if (c == 0) atomicAdd(&counts[curg], (float)(end - runStart));
}

// ---------------- final: sigmoid(mean . linW + b) ----------------------------
__global__ __launch_bounds__(256) void final_kernel(const float* __restrict__ pooled,
    const float* __restrict__ counts, const float* __restrict__ linW,
    const float* __restrict__ linb, float* __restrict__ out, int G)
{
    int g = blockIdx.x * 4 + (threadIdx.x >> 6);
    int lane = threadIdx.x & 63;
    if (g >= G) return;
    float2 p = ((const float2*)(pooled + (size_t)g * H))[lane];
    float2 w = ((const float2*)linW)[lane];
    float part = p.x * w.x + p.y * w.y;
#pragma unroll
    for (int off = 32; off > 0; off >>= 1)
        part += __shfl_down(part, off, 64);
    if (lane == 0) {
        float cnt = fmaxf(counts[g], 1.0f);
        float z = part / cnt + linb[0];
        out[g] = 1.0f / (1.0f + expf(-z));
    }
}

static inline size_t align4(size_t x) { return (x + 3) & ~(size_t)3; }  // 16B align (in floats)

extern "C" void kernel_launch(void* const* d_in, const int* in_sizes, int n_in,
                              void* d_out, int out_size, void* d_ws, size_t ws_size,
                              hipStream_t stream)
{
    const int* x = (const int*)d_in[0];
    const int* ei = (const int*)d_in[1];
    const int* batch = (const int*)d_in[2];
    const float* table = (const float*)d_in[3];
    const float* convW = (const float*)d_in[4];
    const float* convB = (const float*)d_in[5];
    const float* gamma = (const float*)d_in[6];
    const float* beta = (const float*)d_in[7];
    const float* linW = (const float*)d_in[8];
    const float* linb = (const float*)d_in[9];
    float* out = (float*)d_out;

    int N = in_sizes[0] / 9;
    int E = in_sizes[1] / 2;
    int G = out_size;
    int L = in_sizes[4] / (H * H);
    const int* row = ei;
    const int* col = ei + E;
    int NB = (N + 255) / 256;  // blocks for scan (must be <= 512)

    float* ws = (float*)d_ws;
    size_t off = 0;
    // ---- zeroed region ----
    int* deg = (int*)(ws + off);        off = align4(off + N);
    int* cnt = (int*)(ws + off);        off = align4(off + N);
    float* pooled = ws + off;           off = align4(off + (size_t)G * H);
    float* counts = ws + off;           off = align4(off + G);
    float* stats = ws + off;            off = align4(off + (size_t)L * 4 * H);
    size_t zero_bytes = off * sizeof(float);
    // ---- non-zeroed ----
    float* dis = ws + off;              off = align4(off + N);
    int* row_ptr = (int*)(ws + off);    off = align4(off + N + 1);
    int* blockSums = (int*)(ws + off);  off = align4(off + 512);
    unsigned short* wt = (unsigned short*)(ws + off); off = align4(off + (size_t)L * H * H);  // L*2*H*H ushort
    float2* edge_data = (float2*)(ws + off); off = align4(off + (size_t)2 * E);
    float* A = ws + off;                off += (size_t)N * H;
    unsigned short* B = (unsigned short*)(ws + off); off = align4(off + (size_t)N * H / 2);  // bf16 ht
    float* C = ws + off;                off += (size_t)N * H;

    hipMemsetAsync(d_ws, 0, zero_bytes, stream);

    enc_kernel<<<(N * 128 + 255) / 256, 256, 0, stream>>>(x, table, A, N);
    deg_kernel<<<(E + 255) / 256, 256, 0, stream>>>(col, deg, E);
    dis_kernel<<<(N + 255) / 256, 256, 0, stream>>>(deg, dis, N);
    scan1_kernel<<<NB, 256, 0, stream>>>(deg, blockSums, N);
    scan2_kernel<<<1, 512, 0, stream>>>(blockSums, NB);
    scan3_kernel<<<NB, 256, 0, stream>>>(deg, blockSums, row_ptr, N, E);
    fill_kernel<<<(E + 255) / 256, 256, 0, stream>>>(row, col, row_ptr, cnt, dis, edge_data, E);
    wprep_kernel<<<L * 128, 128, 0, stream>>>(convW, wt, L);

    int gemmBlocks = (N + 127) / 128;
    for (int l = 0; l < L; ++l) {
        float* st = stats + (size_t)l * 4 * H;
        const unsigned short* wthi = wt + (size_t)l * 2 * H * H;
        gemm_mfma_kernel<<<gemmBlocks, 256, 0, stream>>>(A, wthi, B, N);
        agg_kernel<<<(N + 3) / 4, 256, 0, stream>>>(B, row_ptr, edge_data, dis,
                                                    convB + (size_t)l * H, C, N);
        bn_reduce_kernel<<<NB, 256, 0, stream>>>(C, st, N);
        bn_finalize_kernel<<<1, 128, 0, stream>>>(st, gamma + (size_t)l * H, beta + (size_t)l * H, 1.0f / (float)N);
        bn_apply_kernel<<<(N * 32 + 255) / 256, 256, 0, stream>>>(C, st, A, N, (l < L - 1) ? 1 : 0);
    }

    pool_kernel<<<(N + POOL_ROWS - 1) / POOL_ROWS, 128, 0, stream>>>(A, batch, pooled, counts, N);
    final_kernel<<<(G + 3) / 4, 256, 0, stream>>>(pooled, counts, linW, linb, out, G);
}